// Round 9
// baseline (281.981 us; speedup 1.0000x reference)
//
#include <hip/hip_runtime.h>

#define N_NODES 50000
#define N_EDGES 800000
#define K_BR    8
#define N_BUK   56               // bucket = (d>>13)*8 + branch ; d>>13 in [0,6]
#define SUB     20480            // slots/bucket; /64 and /256 aligned; mean fill 16.4K, sigma ~127
#define MLP_SLOTS (N_BUK * SUB)  // 1,146,880
#define SCAN_BLOCKS 196          // ceil(50000/256)

// ---------------- workspace layout (bytes) ----------------
// fbuf      : 800,000 rows x 64 B bf16   @ 0           (51,200,000)
// payload   : MLP_SLOTS x 32 B           @ 51,200,000  (36,700,160) [fill-guarded, no memset]
// cnt(deg)  : N ints                     @ 87,900,160  (200,000)
// bucketCur : 56 ints (fill counts)      @ 88,100,160  (224)
// nodeStart : N ints                     @ 88,100,384  (200,000)
// blockSums : 256 ints                   @ 88,300,384  (1,024)
// blockOffs : 256 ints                   @ 88,301,408  (1,024)
// total: 88,302,432  (< proven ws floor 109,473,920)

__device__ __forceinline__ int branch_idx(float dx, float dy) {
    return (dx > 0.0f ? 1 : 0) + (dy > 0.0f ? 2 : 0) +
           ((fabsf(dx) - fabsf(dy)) > 0.0f ? 4 : 0);
}

__device__ __forceinline__ unsigned int pk_bf16(float a, float b) {
    unsigned int ua = __float_as_uint(a), ub = __float_as_uint(b);
    ua += 0x7FFFu + ((ua >> 16) & 1u);   // round-to-nearest-even
    ub += 0x7FFFu + ((ub >> 16) & 1u);
    return (ua >> 16) | (ub & 0xFFFF0000u);
}

// ONE pass over edges: 56-bucket scatter of packed 32B edge records + CSR rank.
// Bucket = (d-octant)*8 + branch: consecutive mlp waves share both the weight
// set AND a 1MB x[d] octant (L2-resident). Payload writes are frontier-dense
// per bucket -> L2 write-merge. 800000 = 3125*256 exactly -> no bounds check.
// After the grid completes, bucketCur[b] == fill count of bucket b.
__global__ void pass1_kernel(const int* __restrict__ ei, const float* __restrict__ pos,
                             const float* __restrict__ ea, const float* __restrict__ ew,
                             int* __restrict__ cnt, int* __restrict__ bucketCur,
                             uint4* __restrict__ payload) {
    __shared__ int h[N_BUK];
    __shared__ int base[N_BUK];
    int t = threadIdx.x;
    if (t < N_BUK) h[t] = 0;
    __syncthreads();
    int e = blockIdx.x * 256 + t;
    int s = ei[e], d = ei[N_EDGES + e];
    float2 ps = ((const float2*)pos)[s];
    float2 pd = ((const float2*)pos)[d];
    int k = branch_idx(ps.x - pd.x, ps.y - pd.y);
    int bucket = ((d >> 13) << 3) | k;
    int rank = atomicAdd(&h[bucket], 1);
    int slotLocal = atomicAdd(&cnt[d], 1);
    __syncthreads();
    if (t < N_BUK) base[t] = (h[t] > 0) ? atomicAdd(&bucketCur[t], h[t]) : 0;
    __syncthreads();
    int idx = bucket * SUB + base[bucket] + rank;
    float4 eav = ((const float4*)ea)[e];
    uint4 r0, r1;
    r0.x = (unsigned)s; r0.y = (unsigned)d; r0.z = (unsigned)slotLocal;
    r0.w = __float_as_uint(ew[e]);
    r1.x = __float_as_uint(eav.x); r1.y = __float_as_uint(eav.y);
    r1.z = __float_as_uint(eav.z); r1.w = __float_as_uint(eav.w);
    payload[2 * (size_t)idx]     = r0;
    payload[2 * (size_t)idx + 1] = r1;
}

// ---- parallel hierarchical exclusive scan of cnt[N] -> nodeStart[N] ----
// (R7 lesson: single-block fused scan = 95us latency-bound; this 3-kernel
//  version is ~5us total across 196 blocks.)
__global__ void scanA_kernel(const int* __restrict__ cnt, int* __restrict__ nodeStart,
                             int* __restrict__ blockSums) {
    __shared__ int s[256];
    int t = threadIdx.x;
    int i = blockIdx.x * 256 + t;
    int v = (i < N_NODES) ? cnt[i] : 0;
    s[t] = v;
    __syncthreads();
#pragma unroll
    for (int off = 1; off < 256; off <<= 1) {
        int tmp = (t >= off) ? s[t - off] : 0;
        __syncthreads();
        s[t] += tmp;
        __syncthreads();
    }
    if (i < N_NODES) nodeStart[i] = s[t] - v;  // exclusive
    if (t == 255) blockSums[blockIdx.x] = s[255];
}

__global__ void scanB_kernel(const int* __restrict__ blockSums, int* __restrict__ blockOffs) {
    __shared__ int s[256];
    int t = threadIdx.x;
    int v = (t < SCAN_BLOCKS) ? blockSums[t] : 0;
    s[t] = v;
    __syncthreads();
#pragma unroll
    for (int off = 1; off < 256; off <<= 1) {
        int tmp = (t >= off) ? s[t - off] : 0;
        __syncthreads();
        s[t] += tmp;
        __syncthreads();
    }
    blockOffs[t] = s[t] - v;
}

__global__ void scanC_kernel(int* __restrict__ nodeStart, const int* __restrict__ blockOffs) {
    int i = blockIdx.x * 256 + threadIdx.x;
    if (i < N_NODES) nodeStart[i] += blockOffs[blockIdx.x];
}

// R5-proven 1-edge-per-lane MLP (VGPR ~40; R6 lesson: 2 edges/lane spills).
// R9: single coalesced payload read replaces the perm->e->{ei,ea,ew} gather
// chain; only x rows remain gathered (x[d] is octant-local).
__global__ void __launch_bounds__(256) mlp_kernel(
    const uint4* __restrict__ payload, const float* __restrict__ x,
    const float* __restrict__ W1, const float* __restrict__ b1,
    const float* __restrict__ W2, const float* __restrict__ b2,
    const int* __restrict__ nodeStart, const int* __restrict__ bucketFill,
    unsigned short* __restrict__ fbuf) {
    int t = blockIdx.x * 256 + threadIdx.x;
    // wave-uniform bucket id + fill count (R4 lesson: must be readfirstlane-
    // derived or the 2304 weight loads become per-lane global_loads).
    int u = __builtin_amdgcn_readfirstlane(t);
    int bucket = u / SUB;               // SUB is 256-aligned: wave spans 1 bucket
    int fill = bucketFill[bucket];
    if (u - bucket * SUB >= fill) return;       // whole wave past bucket fill
    int rel = t - bucket * SUB;
    bool valid = rel < fill;
    int idx = bucket * SUB + min(rel, fill - 1);  // clamp: pad slots are garbage
    uint4 r0 = payload[2 * (size_t)idx];
    uint4 r1 = payload[2 * (size_t)idx + 1];
    int s = (int)r0.x, d = (int)r0.y;
    float w = __uint_as_float(r0.w);
    int k = bucket & 7;                 // wave-uniform branch id

    float m[36];
    const float4* xj = (const float4*)(x + 32 * (size_t)s);
    const float4* xi = (const float4*)(x + 32 * (size_t)d);
#pragma unroll
    for (int q = 0; q < 8; ++q) {
        float4 a = xj[q], b = xi[q];
        m[4 * q + 0] = a.x - b.x;
        m[4 * q + 1] = a.y - b.y;
        m[4 * q + 2] = a.z - b.z;
        m[4 * q + 3] = a.w - b.w;
    }
    m[32] = __uint_as_float(r1.x); m[33] = __uint_as_float(r1.y);
    m[34] = __uint_as_float(r1.z); m[35] = __uint_as_float(r1.w);
    int slot = nodeStart[d] + (int)r0.z;   // nodeStart is 200KB -> L2-resident

    // Layer 1: c-outer / o-inner -> weights stream contiguously in the
    // ORIGINAL [k][c][o] layout (no transpose), sequential s_load bursts.
    const float* w1  = W1 + k * (36 * 32);
    const float* bb1 = b1 + k * 32;
    float acc[32];
#pragma unroll
    for (int o = 0; o < 32; ++o) acc[o] = bb1[o];
#pragma unroll
    for (int c = 0; c < 36; ++c) {
        float mc = m[c];
#pragma unroll
        for (int o = 0; o < 32; ++o) acc[o] = fmaf(mc, w1[c * 32 + o], acc[o]);
    }
#pragma unroll
    for (int o = 0; o < 32; ++o) acc[o] = fmaxf(acc[o], 0.0f);

    // Layer 2: o-outer / g-inner, original [k][o][g] layout.
    const float* w2  = W2 + k * (32 * 32);
    const float* bb2 = b2 + k * 32;
    float acc2[32];
#pragma unroll
    for (int g = 0; g < 32; ++g) acc2[g] = bb2[g];
#pragma unroll
    for (int o = 0; o < 32; ++o) {
        float ho = acc[o];
#pragma unroll
        for (int g = 0; g < 32; ++g) acc2[g] = fmaf(ho, w2[o * 32 + g], acc2[g]);
    }

    // store bf16 row (full 64B line) directly at the CSR slot
    uint4* frow = (uint4*)(fbuf + 32 * (size_t)slot);
#pragma unroll
    for (int q = 0; q < 4; ++q) {
        uint4 r;
        r.x = pk_bf16(fmaxf(acc2[8 * q + 0], 0.0f) * w, fmaxf(acc2[8 * q + 1], 0.0f) * w);
        r.y = pk_bf16(fmaxf(acc2[8 * q + 2], 0.0f) * w, fmaxf(acc2[8 * q + 3], 0.0f) * w);
        r.z = pk_bf16(fmaxf(acc2[8 * q + 4], 0.0f) * w, fmaxf(acc2[8 * q + 5], 0.0f) * w);
        r.w = pk_bf16(fmaxf(acc2[8 * q + 6], 0.0f) * w, fmaxf(acc2[8 * q + 7], 0.0f) * w);
        if (valid) frow[q] = r;
    }
}

// 2 channels per thread: uint read = 2 bf16 -> 256B/wave-inst fbuf streaming.
__global__ void agg_kernel(const unsigned short* __restrict__ fbuf,
                           const int* __restrict__ nodeStart, const int* __restrict__ deg,
                           const float* __restrict__ x, const float* __restrict__ Wr,
                           const float* __restrict__ br, float* __restrict__ out) {
    int t = blockIdx.x * blockDim.x + threadIdx.x;
    if (t >= N_NODES * 16) return;
    int n = t >> 4, hc = t & 15;          // channels 2*hc, 2*hc+1
    int st = nodeStart[n], dg = deg[n];
    const unsigned int* fb = (const unsigned int*)fbuf;
    float acc0 = 0.0f, acc1 = 0.0f;
    for (int j = 0; j < dg; ++j) {
        unsigned int u = fb[(size_t)(st + j) * 16 + hc];  // CSR-contiguous stream
        acc0 += __uint_as_float(u << 16);
        acc1 += __uint_as_float(u & 0xFFFF0000u);
    }
    float inv = 1.0f / (float)max(dg, 1);
    int o = hc * 2;
    acc0 = acc0 * inv + br[o];
    acc1 = acc1 * inv + br[o + 1];
    const float* xr = x + 32 * (size_t)n;
#pragma unroll
    for (int c = 0; c < 32; ++c) {
        float xv = xr[c];
        acc0 = fmaf(xv, Wr[c * 32 + o], acc0);
        acc1 = fmaf(xv, Wr[c * 32 + o + 1], acc1);
    }
    float2* o2 = (float2*)(out + 32 * (size_t)n + o);
    *o2 = make_float2(acc0, acc1);
}

extern "C" void kernel_launch(void* const* d_in, const int* in_sizes, int n_in,
                              void* d_out, int out_size, void* d_ws, size_t ws_size,
                              hipStream_t stream) {
    const float* x   = (const float*)d_in[0];
    const float* pos = (const float*)d_in[1];
    const int*   ei  = (const int*)d_in[2];
    const float* ea  = (const float*)d_in[3];
    const float* ew  = (const float*)d_in[4];
    const float* W1  = (const float*)d_in[5];
    const float* b1  = (const float*)d_in[6];
    const float* W2  = (const float*)d_in[7];
    const float* b2  = (const float*)d_in[8];
    const float* Wr  = (const float*)d_in[9];
    const float* br  = (const float*)d_in[10];
    float* out = (float*)d_out;

    char* ws = (char*)d_ws;
    unsigned short* fbuf = (unsigned short*)(ws + 0);
    uint4* payload = (uint4*)(ws + 51200000);
    int* cnt       = (int*)(ws + 87900160);
    int* bucketCur = (int*)(ws + 88100160);
    int* nodeStart = (int*)(ws + 88100384);
    int* blockSums = (int*)(ws + 88300384);
    int* blockOffs = (int*)(ws + 88301408);

    hipMemsetAsync(cnt, 0, 200224, stream);  // cnt + bucketCur (contiguous)

    pass1_kernel<<<N_EDGES / 256, 256, 0, stream>>>(ei, pos, ea, ew, cnt, bucketCur, payload);
    scanA_kernel<<<SCAN_BLOCKS, 256, 0, stream>>>(cnt, nodeStart, blockSums);
    scanB_kernel<<<1, 256, 0, stream>>>(blockSums, blockOffs);
    scanC_kernel<<<SCAN_BLOCKS, 256, 0, stream>>>(nodeStart, blockOffs);
    mlp_kernel<<<MLP_SLOTS / 256, 256, 0, stream>>>(payload, x, W1, b1, W2, b2,
                                                    nodeStart, bucketCur, fbuf);
    agg_kernel<<<(N_NODES * 16 + 255) / 256, 256, 0, stream>>>(fbuf, nodeStart, cnt,
                                                               x, Wr, br, out);
}

// Round 10
// 254.357 us; speedup vs baseline: 1.1086x; 1.1086x over previous
//
#include <hip/hip_runtime.h>

#define N_NODES 50000
#define N_EDGES 800000
#define K_BR    8
#define BCAP    131072           // per-bucket slot capacity (2^17); mean fill 100K
#define MLP_SLOTS (K_BR * BCAP)  // 1,048,576
#define SCAN_BLOCKS 196          // ceil(50000/256)

typedef _Float16 h2 __attribute__((ext_vector_type(2)));

#if __has_builtin(__builtin_amdgcn_fdot2)
#define FDOT2(a, b, c) __builtin_amdgcn_fdot2((a), (b), (c), false)
#else
#define FDOT2(a, b, c) ((c) + (float)(a).x * (float)(b).x + (float)(a).y * (float)(b).y)
#endif

// ---------------- workspace layout (bytes) ----------------
// fbuf      : 800,000 rows x 64 B bf16   @ 0           (51,200,000)
// perm      : MLP_SLOTS ints             @ 51,200,000  (4,194,304) [fill-guarded, no memset]
// slotLocal : E ints                     @ 55,394,304  (3,200,000)
// cnt(deg)  : N ints                     @ 58,594,304  (200,000)
// bucketCur : 8 ints (fill counts)       @ 58,794,304  (32)
// nodeStart : N ints                     @ 58,794,336  (200,000)
// blockSums : 256 ints                   @ 58,994,336  (1,024)
// blockOffs : 256 ints                   @ 58,995,360  (1,024)
// W1p       : 8*18*32 uints (f16x2)      @ 58,996,384  (18,432)
// W2p       : 8*16*32 uints (f16x2)      @ 59,014,816  (16,384)
// total: 59,031,200  (< proven ws floor 109,473,920)

__device__ __forceinline__ int branch_idx(float dx, float dy) {
    return (dx > 0.0f ? 1 : 0) + (dy > 0.0f ? 2 : 0) +
           ((fabsf(dx) - fabsf(dy)) > 0.0f ? 4 : 0);
}

__device__ __forceinline__ unsigned int pk_bf16(float a, float b) {
    unsigned int ua = __float_as_uint(a), ub = __float_as_uint(b);
    ua += 0x7FFFu + ((ua >> 16) & 1u);   // round-to-nearest-even
    ub += 0x7FFFu + ((ub >> 16) & 1u);
    return (ua >> 16) | (ub & 0xFFFF0000u);
}

// pack W1 [k][c][o] -> W1p [k][cp][o] f16x2 over (2cp,2cp+1); same for W2 over o-pairs.
__global__ void prep_kernel(const float* __restrict__ W1, const float* __restrict__ W2,
                            unsigned* __restrict__ W1p, unsigned* __restrict__ W2p) {
    int t = blockIdx.x * 256 + threadIdx.x;   // grid = 34*256 = 8704 exactly
    if (t < 4608) {
        int k = t / 576, r = t % 576;
        int cp = r / 32, o = r % 32;
        h2 p;
        p.x = (_Float16)W1[k * 1152 + (2 * cp) * 32 + o];
        p.y = (_Float16)W1[k * 1152 + (2 * cp + 1) * 32 + o];
        W1p[t] = __builtin_bit_cast(unsigned, p);
    } else {
        int u = t - 4608;
        int k = u / 512, r = u % 512;
        int op = r / 32, g = r % 32;
        h2 p;
        p.x = (_Float16)W2[k * 1024 + (2 * op) * 32 + g];
        p.y = (_Float16)W2[k * 1024 + (2 * op + 1) * 32 + g];
        W2p[u + 4608 - 4608 + 0] = 0;  // placeholder avoided below
        W2p[u] = __builtin_bit_cast(unsigned, p);
    }
}

// ONE pass over edges: branch histogram + bucket scatter (perm) + CSR rank.
// 800000 = 3125 * 256 exactly -> no bounds check.
// After the grid completes, bucketCur[k] == total edges in bucket k.
__global__ void pass1_kernel(const int* __restrict__ ei, const float* __restrict__ pos,
                             int* __restrict__ cnt, int* __restrict__ slotLocal,
                             int* __restrict__ bucketCur, int* __restrict__ perm) {
    __shared__ int h[K_BR];
    __shared__ int base[K_BR];
    int t = threadIdx.x;
    if (t < K_BR) h[t] = 0;
    __syncthreads();
    int e = blockIdx.x * 256 + t;
    int s = ei[e], d = ei[N_EDGES + e];
    float2 ps = ((const float2*)pos)[s];
    float2 pd = ((const float2*)pos)[d];
    int k = branch_idx(ps.x - pd.x, ps.y - pd.y);
    int rank = atomicAdd(&h[k], 1);
    slotLocal[e] = atomicAdd(&cnt[d], 1);
    __syncthreads();
    if (t < K_BR) base[t] = (h[t] > 0) ? atomicAdd(&bucketCur[t], h[t]) : 0;
    __syncthreads();
    perm[(k << 17) + base[k] + rank] = e;
}

// ---- parallel hierarchical exclusive scan of cnt[N] -> nodeStart[N] ----
// (R7 lesson: single-block fused scan = 95us latency-bound; this 3-kernel
//  version is ~5us total across 196 blocks.)
__global__ void scanA_kernel(const int* __restrict__ cnt, int* __restrict__ nodeStart,
                             int* __restrict__ blockSums) {
    __shared__ int s[256];
    int t = threadIdx.x;
    int i = blockIdx.x * 256 + t;
    int v = (i < N_NODES) ? cnt[i] : 0;
    s[t] = v;
    __syncthreads();
#pragma unroll
    for (int off = 1; off < 256; off <<= 1) {
        int tmp = (t >= off) ? s[t - off] : 0;
        __syncthreads();
        s[t] += tmp;
        __syncthreads();
    }
    if (i < N_NODES) nodeStart[i] = s[t] - v;  // exclusive
    if (t == 255) blockSums[blockIdx.x] = s[255];
}

__global__ void scanB_kernel(const int* __restrict__ blockSums, int* __restrict__ blockOffs) {
    __shared__ int s[256];
    int t = threadIdx.x;
    int v = (t < SCAN_BLOCKS) ? blockSums[t] : 0;
    s[t] = v;
    __syncthreads();
#pragma unroll
    for (int off = 1; off < 256; off <<= 1) {
        int tmp = (t >= off) ? s[t - off] : 0;
        __syncthreads();
        s[t] += tmp;
        __syncthreads();
    }
    blockOffs[t] = s[t] - v;
}

__global__ void scanC_kernel(int* __restrict__ nodeStart, const int* __restrict__ blockOffs) {
    int i = blockIdx.x * 256 + threadIdx.x;
    if (i < N_NODES) nodeStart[i] += blockOffs[blockIdx.x];
}

// 1-edge-per-lane MLP via v_dot2_f32_f16: f16x2 pair-dots with f32 accumulate.
// VALU ~1100/edge (vs 2400 fp32) and weight s_load stream halved (1152 dwords).
// (R4 lesson: k must be readfirstlane-derived for s_load weights.
//  R6 lesson: don't add per-lane state - VGPR spill cliff.)
__global__ void __launch_bounds__(256) mlp_kernel(
    const int* __restrict__ perm, const int* __restrict__ ei,
    const float* __restrict__ x, const float* __restrict__ ea,
    const float* __restrict__ ew,
    const unsigned* __restrict__ W1p, const float* __restrict__ b1,
    const unsigned* __restrict__ W2p, const float* __restrict__ b2,
    const int* __restrict__ nodeStart, const int* __restrict__ slotLocal,
    const int* __restrict__ bucketFill,
    unsigned short* __restrict__ fbuf) {
    int t = blockIdx.x * 256 + threadIdx.x;
    int u = __builtin_amdgcn_readfirstlane(t);
    int k = u >> 17;
    int fill = bucketFill[k];
    if ((u & (BCAP - 1)) >= fill) return;   // whole wave past bucket fill
    int rel = t & (BCAP - 1);
    bool valid = rel < fill;
    int e = perm[(k << 17) + min(rel, fill - 1)];  // clamp: pad slots are garbage

    int s = ei[e];
    int d = ei[N_EDGES + e];

    h2 mp[18];
    const float4* xj = (const float4*)(x + 32 * (size_t)s);
    const float4* xi = (const float4*)(x + 32 * (size_t)d);
#pragma unroll
    for (int q = 0; q < 8; ++q) {
        float4 a = xj[q], b = xi[q];
        h2 p0, p1;
        p0.x = (_Float16)(a.x - b.x); p0.y = (_Float16)(a.y - b.y);
        p1.x = (_Float16)(a.z - b.z); p1.y = (_Float16)(a.w - b.w);
        mp[2 * q] = p0; mp[2 * q + 1] = p1;
    }
    float4 eav = ((const float4*)ea)[e];
    { h2 p; p.x = (_Float16)eav.x; p.y = (_Float16)eav.y; mp[16] = p; }
    { h2 p; p.x = (_Float16)eav.z; p.y = (_Float16)eav.w; mp[17] = p; }
    float w = ew[e];
    int slot = valid ? (nodeStart[d] + slotLocal[e]) : 0;

    // Layer 1: cp-outer / o-inner; W1p streams contiguously (s_load bursts).
    const unsigned* w1 = W1p + k * 576;
    const float* bb1 = b1 + k * 32;
    float acc[32];
#pragma unroll
    for (int o = 0; o < 32; ++o) acc[o] = bb1[o];
#pragma unroll
    for (int cp = 0; cp < 18; ++cp) {
        h2 m2 = mp[cp];
#pragma unroll
        for (int o = 0; o < 32; ++o)
            acc[o] = FDOT2(m2, __builtin_bit_cast(h2, w1[cp * 32 + o]), acc[o]);
    }
    // ReLU + pack h into f16x2 pairs
    h2 hp[16];
#pragma unroll
    for (int op = 0; op < 16; ++op) {
        h2 p;
        p.x = (_Float16)fmaxf(acc[2 * op], 0.0f);
        p.y = (_Float16)fmaxf(acc[2 * op + 1], 0.0f);
        hp[op] = p;
    }

    // Layer 2: op-outer / g-inner.
    const unsigned* w2 = W2p + k * 512;
    const float* bb2 = b2 + k * 32;
    float acc2[32];
#pragma unroll
    for (int g = 0; g < 32; ++g) acc2[g] = bb2[g];
#pragma unroll
    for (int op = 0; op < 16; ++op) {
        h2 hv = hp[op];
#pragma unroll
        for (int g = 0; g < 32; ++g)
            acc2[g] = FDOT2(hv, __builtin_bit_cast(h2, w2[op * 32 + g]), acc2[g]);
    }

    // store bf16 row (full 64B line) directly at the CSR slot
    uint4* frow = (uint4*)(fbuf + 32 * (size_t)slot);
#pragma unroll
    for (int q = 0; q < 4; ++q) {
        uint4 r;
        r.x = pk_bf16(fmaxf(acc2[8 * q + 0], 0.0f) * w, fmaxf(acc2[8 * q + 1], 0.0f) * w);
        r.y = pk_bf16(fmaxf(acc2[8 * q + 2], 0.0f) * w, fmaxf(acc2[8 * q + 3], 0.0f) * w);
        r.z = pk_bf16(fmaxf(acc2[8 * q + 4], 0.0f) * w, fmaxf(acc2[8 * q + 5], 0.0f) * w);
        r.w = pk_bf16(fmaxf(acc2[8 * q + 6], 0.0f) * w, fmaxf(acc2[8 * q + 7], 0.0f) * w);
        if (valid) frow[q] = r;
    }
}

// 2 channels per thread: uint read = 2 bf16 -> 256B/wave-inst fbuf streaming.
__global__ void agg_kernel(const unsigned short* __restrict__ fbuf,
                           const int* __restrict__ nodeStart, const int* __restrict__ deg,
                           const float* __restrict__ x, const float* __restrict__ Wr,
                           const float* __restrict__ br, float* __restrict__ out) {
    int t = blockIdx.x * blockDim.x + threadIdx.x;
    if (t >= N_NODES * 16) return;
    int n = t >> 4, hc = t & 15;          // channels 2*hc, 2*hc+1
    int st = nodeStart[n], dg = deg[n];
    const unsigned int* fb = (const unsigned int*)fbuf;
    float acc0 = 0.0f, acc1 = 0.0f;
    for (int j = 0; j < dg; ++j) {
        unsigned int u = fb[(size_t)(st + j) * 16 + hc];  // CSR-contiguous stream
        acc0 += __uint_as_float(u << 16);
        acc1 += __uint_as_float(u & 0xFFFF0000u);
    }
    float inv = 1.0f / (float)max(dg, 1);
    int o = hc * 2;
    acc0 = acc0 * inv + br[o];
    acc1 = acc1 * inv + br[o + 1];
    const float* xr = x + 32 * (size_t)n;
#pragma unroll
    for (int c = 0; c < 32; ++c) {
        float xv = xr[c];
        acc0 = fmaf(xv, Wr[c * 32 + o], acc0);
        acc1 = fmaf(xv, Wr[c * 32 + o + 1], acc1);
    }
    float2* o2 = (float2*)(out + 32 * (size_t)n + o);
    *o2 = make_float2(acc0, acc1);
}

extern "C" void kernel_launch(void* const* d_in, const int* in_sizes, int n_in,
                              void* d_out, int out_size, void* d_ws, size_t ws_size,
                              hipStream_t stream) {
    const float* x   = (const float*)d_in[0];
    const float* pos = (const float*)d_in[1];
    const int*   ei  = (const int*)d_in[2];
    const float* ea  = (const float*)d_in[3];
    const float* ew  = (const float*)d_in[4];
    const float* W1  = (const float*)d_in[5];
    const float* b1  = (const float*)d_in[6];
    const float* W2  = (const float*)d_in[7];
    const float* b2  = (const float*)d_in[8];
    const float* Wr  = (const float*)d_in[9];
    const float* br  = (const float*)d_in[10];
    float* out = (float*)d_out;

    char* ws = (char*)d_ws;
    unsigned short* fbuf = (unsigned short*)(ws + 0);
    int* perm      = (int*)(ws + 51200000);
    int* slotLocal = (int*)(ws + 55394304);
    int* cnt       = (int*)(ws + 58594304);
    int* bucketCur = (int*)(ws + 58794304);
    int* nodeStart = (int*)(ws + 58794336);
    int* blockSums = (int*)(ws + 58994336);
    int* blockOffs = (int*)(ws + 58995360);
    unsigned* W1p  = (unsigned*)(ws + 58996384);
    unsigned* W2p  = (unsigned*)(ws + 59014816);

    hipMemsetAsync(cnt, 0, 200032, stream);  // cnt + bucketCur (contiguous)

    prep_kernel<<<34, 256, 0, stream>>>(W1, W2, W1p, W2p);
    pass1_kernel<<<N_EDGES / 256, 256, 0, stream>>>(ei, pos, cnt, slotLocal, bucketCur, perm);
    scanA_kernel<<<SCAN_BLOCKS, 256, 0, stream>>>(cnt, nodeStart, blockSums);
    scanB_kernel<<<1, 256, 0, stream>>>(blockSums, blockOffs);
    scanC_kernel<<<SCAN_BLOCKS, 256, 0, stream>>>(nodeStart, blockOffs);
    mlp_kernel<<<MLP_SLOTS / 256, 256, 0, stream>>>(perm, ei, x, ea, ew,
                                                    W1p, b1, W2p, b2,
                                                    nodeStart, slotLocal, bucketCur, fbuf);
    agg_kernel<<<(N_NODES * 16 + 255) / 256, 256, 0, stream>>>(fbuf, nodeStart, cnt,
                                                               x, Wr, br, out);
}

// Round 11
// 234.236 us; speedup vs baseline: 1.2038x; 1.0859x over previous
//
#include <hip/hip_runtime.h>

#define N_NODES 50000
#define N_EDGES 800000
#define K_BR    8
#define BCAP    131072           // per-bucket slot capacity (2^17); mean fill 100K
#define MLP_SLOTS (K_BR * BCAP)  // 1,048,576
#define SCAN_BLOCKS 196          // ceil(50000/256)

typedef _Float16 h2 __attribute__((ext_vector_type(2)));

#if __has_builtin(__builtin_amdgcn_fdot2)
#define FDOT2(a, b, c) __builtin_amdgcn_fdot2((a), (b), (c), false)
#else
#define FDOT2(a, b, c) ((c) + (float)(a).x * (float)(b).x + (float)(a).y * (float)(b).y)
#endif

#define VAL_MASK 0x3FFFFFFFu
#define FLG_A    0x40000000u
#define FLG_P    0x80000000u

// ---------------- workspace layout (bytes) ----------------
// fbuf      : 800,000 rows x 64 B bf16   @ 0           (51,200,000)
// perm      : MLP_SLOTS ints             @ 51,200,000  (4,194,304) [fill-guarded, no memset]
// slotLocal : E ints                     @ 55,394,304  (3,200,000)
// cnt(deg)  : N ints                     @ 58,594,304  (200,000)   [memset 0]
// bucketCur : 8 ints (fill counts)       @ 58,794,304  (32)        [memset 0]
// ps        : 196 uints (lookback)       @ 58,794,336  (784+pad)   [memset 0]
// nodeStart : N ints                     @ 58,795,136  (200,000)
// W1p       : 8*18*32 uints (f16x2)      @ 58,995,136  (18,432)
// W2p       : 8*16*32 uints (f16x2)      @ 59,013,568  (16,384)
// xh        : 50,000 x 32 bf16           @ 59,029,952  (3,200,000)
// total: 62,229,952  (< proven ws floor 109,473,920)

__device__ __forceinline__ int branch_idx(float dx, float dy) {
    return (dx > 0.0f ? 1 : 0) + (dy > 0.0f ? 2 : 0) +
           ((fabsf(dx) - fabsf(dy)) > 0.0f ? 4 : 0);
}

__device__ __forceinline__ unsigned int pk_bf16(float a, float b) {
    unsigned int ua = __float_as_uint(a), ub = __float_as_uint(b);
    ua += 0x7FFFu + ((ua >> 16) & 1u);   // round-to-nearest-even
    ub += 0x7FFFu + ((ub >> 16) & 1u);
    return (ua >> 16) | (ub & 0xFFFF0000u);
}

__device__ __forceinline__ unsigned pk_f16pair(float a, float b) {
    h2 p; p.x = (_Float16)a; p.y = (_Float16)b;
    return __builtin_bit_cast(unsigned, p);
}

// pack W1 [k][c][o] -> f16x2 pairs over c; W2 [k][o][g] -> f16x2 pairs over o;
// and mirror x into bf16 (3.2MB -> fits a 4MB per-XCD L2 -> gather = L2 hit).
__global__ void prep_kernel(const float* __restrict__ W1, const float* __restrict__ W2,
                            const float* __restrict__ x,
                            unsigned* __restrict__ W1p, unsigned* __restrict__ W2p,
                            unsigned* __restrict__ xh) {
    int t = blockIdx.x * 256 + threadIdx.x;   // grid = 1600*256 = 409,600
    if (t < 4608) {
        int k = t / 576, r = t % 576, cp = r / 32, o = r % 32;
        W1p[t] = pk_f16pair(W1[k * 1152 + (2 * cp) * 32 + o],
                            W1[k * 1152 + (2 * cp + 1) * 32 + o]);
    } else if (t < 8704) {
        int u = t - 4608;
        int k = u / 512, r = u % 512, op = r / 32, g = r % 32;
        W2p[u] = pk_f16pair(W2[k * 1024 + (2 * op) * 32 + g],
                            W2[k * 1024 + (2 * op + 1) * 32 + g]);
    }
#pragma unroll
    for (int rep = 0; rep < 2; ++rep) {
        int j = t + rep * 409600;
        if (j < 800000) {
            float2 xv = ((const float2*)x)[j];
            xh[j] = pk_bf16(xv.x, xv.y);
        }
    }
}

// ONE pass over edges: branch histogram + bucket scatter (perm) + CSR rank.
// 800000 = 3125 * 256 exactly -> no bounds check.
// After the grid completes, bucketCur[k] == total edges in bucket k.
__global__ void pass1_kernel(const int* __restrict__ ei, const float* __restrict__ pos,
                             int* __restrict__ cnt, int* __restrict__ slotLocal,
                             int* __restrict__ bucketCur, int* __restrict__ perm) {
    __shared__ int h[K_BR];
    __shared__ int base[K_BR];
    int t = threadIdx.x;
    if (t < K_BR) h[t] = 0;
    __syncthreads();
    int e = blockIdx.x * 256 + t;
    int s = ei[e], d = ei[N_EDGES + e];
    float2 ps = ((const float2*)pos)[s];
    float2 pd = ((const float2*)pos)[d];
    int k = branch_idx(ps.x - pd.x, ps.y - pd.y);
    int rank = atomicAdd(&h[k], 1);
    slotLocal[e] = atomicAdd(&cnt[d], 1);
    __syncthreads();
    if (t < K_BR) base[t] = (h[t] > 0) ? atomicAdd(&bucketCur[t], h[t]) : 0;
    __syncthreads();
    perm[(k << 17) + base[k] + rank] = e;
}

// single-dispatch decoupled-lookback exclusive scan of cnt[N] -> nodeStart[N].
// 196 blocks all co-resident (196 < 256 CUs) -> spin-wait cannot deadlock.
// ps[b] packs value (30b) | status (A=aggregate, P=inclusive prefix).
// (R7 lesson: single-BLOCK scan = 95us; this keeps 196-block parallelism.)
__global__ void scan_kernel(const int* __restrict__ cnt, unsigned* __restrict__ ps,
                            int* __restrict__ nodeStart) {
    __shared__ int s[256];
    __shared__ int sh_off;
    int t = threadIdx.x, b = blockIdx.x;
    int i = b * 256 + t;
    int v = (i < N_NODES) ? cnt[i] : 0;
    s[t] = v;
    __syncthreads();
#pragma unroll
    for (int off = 1; off < 256; off <<= 1) {
        int tmp = (t >= off) ? s[t - off] : 0;
        __syncthreads();
        s[t] += tmp;
        __syncthreads();
    }
    int excl = s[t] - v;
    if (t == 255)
        atomicExch(&ps[b], (unsigned)s[255] | (b == 0 ? FLG_P : FLG_A));
    if (t == 0) sh_off = 0;
    if (t < 64 && b > 0) {   // wave-parallel lookback in wave 0
        int off = 0;
        int base = b - 1;
        for (;;) {
            int idx = base - t;
            unsigned w = 0;
            if (idx >= 0) {
                do { w = atomicOr(&ps[idx], 0u); } while (!(w & (FLG_A | FLG_P)));
            }
            bool isP = (w & FLG_P) != 0;
            unsigned long long pm = __ballot(isP);
            int firstP = pm ? (__ffsll((unsigned long long)pm) - 1) : 64;
            int contrib = (idx >= 0 && t <= firstP) ? (int)(w & VAL_MASK) : 0;
#pragma unroll
            for (int sh = 32; sh > 0; sh >>= 1) contrib += __shfl_down(contrib, sh, 64);
            contrib = __shfl(contrib, 0, 64);
            off += contrib;
            if (firstP < 64 || base - 64 < 0) break;
            base -= 64;
        }
        if (t == 0) sh_off = off;
    }
    __syncthreads();
    if (i < N_NODES) nodeStart[i] = excl + sh_off;
}

// 1-edge-per-lane MLP via v_dot2_f32_f16; x gathered from the bf16 mirror
// (1 line/row, L2-resident). (R4 lesson: k must be readfirstlane-derived for
// s_load weights. R6 lesson: no extra per-lane state - VGPR spill cliff.)
__global__ void __launch_bounds__(256) mlp_kernel(
    const int* __restrict__ perm, const int* __restrict__ ei,
    const unsigned* __restrict__ xh, const float* __restrict__ ea,
    const float* __restrict__ ew,
    const unsigned* __restrict__ W1p, const float* __restrict__ b1,
    const unsigned* __restrict__ W2p, const float* __restrict__ b2,
    const int* __restrict__ nodeStart, const int* __restrict__ slotLocal,
    const int* __restrict__ bucketFill,
    unsigned short* __restrict__ fbuf) {
    int t = blockIdx.x * 256 + threadIdx.x;
    int u = __builtin_amdgcn_readfirstlane(t);
    int k = u >> 17;
    int fill = bucketFill[k];
    if ((u & (BCAP - 1)) >= fill) return;   // whole wave past bucket fill
    int rel = t & (BCAP - 1);
    bool valid = rel < fill;
    int e = perm[(k << 17) + min(rel, fill - 1)];  // clamp: pad slots are garbage

    int s = ei[e];
    int d = ei[N_EDGES + e];

    h2 mp[18];
    const uint4* xj = ((const uint4*)xh) + 4 * (size_t)s;   // 64B bf16 row = 4 uint4
    const uint4* xi = ((const uint4*)xh) + 4 * (size_t)d;
#pragma unroll
    for (int q = 0; q < 4; ++q) {
        uint4 a4 = xj[q], b4 = xi[q];
#pragma unroll
        for (int c = 0; c < 4; ++c) {
            unsigned ua = (&a4.x)[c], ub = (&b4.x)[c];
            float d0 = __uint_as_float(ua << 16) - __uint_as_float(ub << 16);
            float d1 = __uint_as_float(ua & 0xFFFF0000u) - __uint_as_float(ub & 0xFFFF0000u);
            h2 p; p.x = (_Float16)d0; p.y = (_Float16)d1;
            mp[4 * q + c] = p;
        }
    }
    float4 eav = ((const float4*)ea)[e];
    { h2 p; p.x = (_Float16)eav.x; p.y = (_Float16)eav.y; mp[16] = p; }
    { h2 p; p.x = (_Float16)eav.z; p.y = (_Float16)eav.w; mp[17] = p; }
    float w = ew[e];
    int slot = valid ? (nodeStart[d] + slotLocal[e]) : 0;

    // Layer 1: cp-outer / o-inner; W1p streams contiguously (s_load bursts).
    const unsigned* w1 = W1p + k * 576;
    const float* bb1 = b1 + k * 32;
    float acc[32];
#pragma unroll
    for (int o = 0; o < 32; ++o) acc[o] = bb1[o];
#pragma unroll
    for (int cp = 0; cp < 18; ++cp) {
        h2 m2 = mp[cp];
#pragma unroll
        for (int o = 0; o < 32; ++o)
            acc[o] = FDOT2(m2, __builtin_bit_cast(h2, w1[cp * 32 + o]), acc[o]);
    }
    // ReLU + pack h into f16x2 pairs
    h2 hp[16];
#pragma unroll
    for (int op = 0; op < 16; ++op) {
        h2 p;
        p.x = (_Float16)fmaxf(acc[2 * op], 0.0f);
        p.y = (_Float16)fmaxf(acc[2 * op + 1], 0.0f);
        hp[op] = p;
    }

    // Layer 2: op-outer / g-inner.
    const unsigned* w2 = W2p + k * 512;
    const float* bb2 = b2 + k * 32;
    float acc2[32];
#pragma unroll
    for (int g = 0; g < 32; ++g) acc2[g] = bb2[g];
#pragma unroll
    for (int op = 0; op < 16; ++op) {
        h2 hv = hp[op];
#pragma unroll
        for (int g = 0; g < 32; ++g)
            acc2[g] = FDOT2(hv, __builtin_bit_cast(h2, w2[op * 32 + g]), acc2[g]);
    }

    // store bf16 row (full 64B line) directly at the CSR slot
    uint4* frow = (uint4*)(fbuf + 32 * (size_t)slot);
#pragma unroll
    for (int q = 0; q < 4; ++q) {
        uint4 r;
        r.x = pk_bf16(fmaxf(acc2[8 * q + 0], 0.0f) * w, fmaxf(acc2[8 * q + 1], 0.0f) * w);
        r.y = pk_bf16(fmaxf(acc2[8 * q + 2], 0.0f) * w, fmaxf(acc2[8 * q + 3], 0.0f) * w);
        r.z = pk_bf16(fmaxf(acc2[8 * q + 4], 0.0f) * w, fmaxf(acc2[8 * q + 5], 0.0f) * w);
        r.w = pk_bf16(fmaxf(acc2[8 * q + 6], 0.0f) * w, fmaxf(acc2[8 * q + 7], 0.0f) * w);
        if (valid) frow[q] = r;
    }
}

// 4 channels per thread: uint2 read = 4 bf16; 8 threads/node cover a 64B row.
__global__ void agg_kernel(const unsigned short* __restrict__ fbuf,
                           const int* __restrict__ nodeStart, const int* __restrict__ deg,
                           const float* __restrict__ x, const float* __restrict__ Wr,
                           const float* __restrict__ br, float* __restrict__ out) {
    int t = blockIdx.x * blockDim.x + threadIdx.x;
    if (t >= N_NODES * 8) return;
    int n = t >> 3, g8 = t & 7;          // channels 4*g8 .. 4*g8+3
    int st = nodeStart[n], dg = deg[n];
    const uint2* fb = (const uint2*)fbuf;
    float a0 = 0.0f, a1 = 0.0f, a2 = 0.0f, a3 = 0.0f;
    for (int j = 0; j < dg; ++j) {
        uint2 uu = fb[(size_t)(st + j) * 8 + g8];   // CSR-contiguous stream
        a0 += __uint_as_float(uu.x << 16);
        a1 += __uint_as_float(uu.x & 0xFFFF0000u);
        a2 += __uint_as_float(uu.y << 16);
        a3 += __uint_as_float(uu.y & 0xFFFF0000u);
    }
    float inv = 1.0f / (float)max(dg, 1);
    int o = g8 * 4;
    a0 = a0 * inv + br[o];
    a1 = a1 * inv + br[o + 1];
    a2 = a2 * inv + br[o + 2];
    a3 = a3 * inv + br[o + 3];
    const float* xr = x + 32 * (size_t)n;
#pragma unroll
    for (int c = 0; c < 32; ++c) {
        float xv = xr[c];
        a0 = fmaf(xv, Wr[c * 32 + o], a0);
        a1 = fmaf(xv, Wr[c * 32 + o + 1], a1);
        a2 = fmaf(xv, Wr[c * 32 + o + 2], a2);
        a3 = fmaf(xv, Wr[c * 32 + o + 3], a3);
    }
    float4* o4 = (float4*)(out + 32 * (size_t)n + o);
    *o4 = make_float4(a0, a1, a2, a3);
}

extern "C" void kernel_launch(void* const* d_in, const int* in_sizes, int n_in,
                              void* d_out, int out_size, void* d_ws, size_t ws_size,
                              hipStream_t stream) {
    const float* x   = (const float*)d_in[0];
    const float* pos = (const float*)d_in[1];
    const int*   ei  = (const int*)d_in[2];
    const float* ea  = (const float*)d_in[3];
    const float* ew  = (const float*)d_in[4];
    const float* W1  = (const float*)d_in[5];
    const float* b1  = (const float*)d_in[6];
    const float* W2  = (const float*)d_in[7];
    const float* b2  = (const float*)d_in[8];
    const float* Wr  = (const float*)d_in[9];
    const float* br  = (const float*)d_in[10];
    float* out = (float*)d_out;

    char* ws = (char*)d_ws;
    unsigned short* fbuf = (unsigned short*)(ws + 0);
    int* perm       = (int*)(ws + 51200000);
    int* slotLocal  = (int*)(ws + 55394304);
    int* cnt        = (int*)(ws + 58594304);
    int* bucketCur  = (int*)(ws + 58794304);
    unsigned* psLb  = (unsigned*)(ws + 58794336);
    int* nodeStart  = (int*)(ws + 58795136);
    unsigned* W1p   = (unsigned*)(ws + 58995136);
    unsigned* W2p   = (unsigned*)(ws + 59013568);
    unsigned* xh    = (unsigned*)(ws + 59029952);

    hipMemsetAsync(cnt, 0, 200832, stream);  // cnt + bucketCur + ps (contiguous)

    prep_kernel<<<1600, 256, 0, stream>>>(W1, W2, x, W1p, W2p, xh);
    pass1_kernel<<<N_EDGES / 256, 256, 0, stream>>>(ei, pos, cnt, slotLocal, bucketCur, perm);
    scan_kernel<<<SCAN_BLOCKS, 256, 0, stream>>>(cnt, psLb, nodeStart);
    mlp_kernel<<<MLP_SLOTS / 256, 256, 0, stream>>>(perm, ei, xh, ea, ew,
                                                    W1p, b1, W2p, b2,
                                                    nodeStart, slotLocal, bucketCur, fbuf);
    agg_kernel<<<(N_NODES * 8 + 255) / 256, 256, 0, stream>>>(fbuf, nodeStart, cnt,
                                                              x, Wr, br, out);
}

// Round 12
// 230.696 us; speedup vs baseline: 1.2223x; 1.0153x over previous
//
#include <hip/hip_runtime.h>

#define N_NODES 50000
#define N_EDGES 800000
#define K_BR    8
#define BCAP    131072           // per-bucket slot capacity (2^17); mean fill 100K
#define MLP_SLOTS (K_BR * BCAP)  // 1,048,576
#define SCAN_BLOCKS 196          // ceil(50000/256)

typedef _Float16 h2 __attribute__((ext_vector_type(2)));
typedef _Float16 half8 __attribute__((ext_vector_type(8)));
typedef float f32x4 __attribute__((ext_vector_type(4)));

#define MFMA(a, b, c) __builtin_amdgcn_mfma_f32_16x16x32_f16((a), (b), (c), 0, 0, 0)

#define VAL_MASK 0x3FFFFFFFu
#define FLG_A    0x40000000u
#define FLG_P    0x80000000u

// ---------------- workspace layout (bytes) ----------------
// fbuf      : 800,000 rows x 64 B bf16   @ 0           (51,200,000)
// perm      : MLP_SLOTS ints             @ 51,200,000  (4,194,304) [fill-guarded, no memset]
// slotLocal : E ints                     @ 55,394,304  (3,200,000)
// cnt(deg)  : N ints                     @ 58,594,304  (200,000)   [memset 0]
// bucketCur : 8 ints (fill counts)       @ 58,794,304  (32)        [memset 0]
// ps        : 196 uints (lookback)       @ 58,794,336  (800)       [memset 0]
// nodeStart : N ints                     @ 58,795,136  (200,000)
// w1f4      : 2048 uint4 (B-frags L1)    @ 58,995,136  (32,768)
// w2f4      : 1024 uint4 (B-frags L2)    @ 59,027,904  (16,384)
// xh        : 50,000 x 32 bf16           @ 59,044,288  (3,200,000)
// total: 62,244,288  (< proven ws floor 109,473,920)

__device__ __forceinline__ int branch_idx(float dx, float dy) {
    return (dx > 0.0f ? 1 : 0) + (dy > 0.0f ? 2 : 0) +
           ((fabsf(dx) - fabsf(dy)) > 0.0f ? 4 : 0);
}

__device__ __forceinline__ unsigned int pk_bf16(float a, float b) {
    unsigned int ua = __float_as_uint(a), ub = __float_as_uint(b);
    ua += 0x7FFFu + ((ua >> 16) & 1u);   // round-to-nearest-even
    ub += 0x7FFFu + ((ub >> 16) & 1u);
    return (ua >> 16) | (ub & 0xFFFF0000u);
}

__device__ __forceinline__ unsigned pk_f16pair(float a, float b) {
    h2 p; p.x = (_Float16)a; p.y = (_Float16)b;
    return __builtin_bit_cast(unsigned, p);
}

__device__ __forceinline__ unsigned short f16bits(float a) {
    _Float16 h = (_Float16)a;
    return __builtin_bit_cast(unsigned short, h);
}

// prep: (1) W1/W2 -> MFMA B-fragment order: B[k=quad*8+j][n=lane&15], frag
// per (kt,nt), 4 dwords (8 f16) per lane. (2) x -> bf16 mirror (3.2MB,
// L2-resident; R11 win). Layouts per m120 (A) / m89 (C/D) verified notes.
__global__ void prep_kernel(const float* __restrict__ W1, const float* __restrict__ W2,
                            const float* __restrict__ x,
                            uint4* __restrict__ w1f4, uint4* __restrict__ w2f4,
                            unsigned* __restrict__ xh) {
    int t = blockIdx.x * 256 + threadIdx.x;   // grid = 1600*256 = 409,600
    if (t < 2048) {                           // layer-1 B frags
        int L = t & 63, fl = t >> 6;
        int nt = fl & 1, kt = (fl >> 1) & 1, k = fl >> 2;
        int quad = L >> 4, col = L & 15;
        unsigned dw[4];
#pragma unroll
        for (int i = 0; i < 4; ++i) {
            float v0 = 0.0f, v1 = 0.0f;
            int k0 = kt * 32 + quad * 8 + 2 * i;
            if (k0 < 36)     v0 = W1[k * 1152 + k0 * 32 + nt * 16 + col];
            if (k0 + 1 < 36) v1 = W1[k * 1152 + (k0 + 1) * 32 + nt * 16 + col];
            dw[i] = pk_f16pair(v0, v1);
        }
        w1f4[t] = make_uint4(dw[0], dw[1], dw[2], dw[3]);
    } else if (t < 3072) {                    // layer-2 B frags
        int u2 = t - 2048;
        int L = u2 & 63, fl = u2 >> 6;
        int nt = fl & 1, k = fl >> 1;
        int quad = L >> 4, col = L & 15;
        unsigned dw[4];
#pragma unroll
        for (int i = 0; i < 4; ++i) {
            int k0 = quad * 8 + 2 * i;
            dw[i] = pk_f16pair(W2[k * 1024 + k0 * 32 + nt * 16 + col],
                               W2[k * 1024 + (k0 + 1) * 32 + nt * 16 + col]);
        }
        w2f4[u2] = make_uint4(dw[0], dw[1], dw[2], dw[3]);
    }
#pragma unroll
    for (int rep = 0; rep < 2; ++rep) {
        int j = t + rep * 409600;
        if (j < 800000) {
            float2 xv = ((const float2*)x)[j];
            xh[j] = pk_bf16(xv.x, xv.y);
        }
    }
}

// ONE pass over edges: branch histogram + bucket scatter (perm) + CSR rank.
// 800000 = 3125 * 256 exactly -> no bounds check.
__global__ void pass1_kernel(const int* __restrict__ ei, const float* __restrict__ pos,
                             int* __restrict__ cnt, int* __restrict__ slotLocal,
                             int* __restrict__ bucketCur, int* __restrict__ perm) {
    __shared__ int h[K_BR];
    __shared__ int base[K_BR];
    int t = threadIdx.x;
    if (t < K_BR) h[t] = 0;
    __syncthreads();
    int e = blockIdx.x * 256 + t;
    int s = ei[e], d = ei[N_EDGES + e];
    float2 ps = ((const float2*)pos)[s];
    float2 pd = ((const float2*)pos)[d];
    int k = branch_idx(ps.x - pd.x, ps.y - pd.y);
    int rank = atomicAdd(&h[k], 1);
    slotLocal[e] = atomicAdd(&cnt[d], 1);
    __syncthreads();
    if (t < K_BR) base[t] = (h[t] > 0) ? atomicAdd(&bucketCur[t], h[t]) : 0;
    __syncthreads();
    perm[(k << 17) + base[k] + rank] = e;
}

// single-dispatch decoupled-lookback exclusive scan (R11-proven).
__global__ void scan_kernel(const int* __restrict__ cnt, unsigned* __restrict__ ps,
                            int* __restrict__ nodeStart) {
    __shared__ int s[256];
    __shared__ int sh_off;
    int t = threadIdx.x, b = blockIdx.x;
    int i = b * 256 + t;
    int v = (i < N_NODES) ? cnt[i] : 0;
    s[t] = v;
    __syncthreads();
#pragma unroll
    for (int off = 1; off < 256; off <<= 1) {
        int tmp = (t >= off) ? s[t - off] : 0;
        __syncthreads();
        s[t] += tmp;
        __syncthreads();
    }
    int excl = s[t] - v;
    if (t == 255)
        atomicExch(&ps[b], (unsigned)s[255] | (b == 0 ? FLG_P : FLG_A));
    if (t == 0) sh_off = 0;
    if (t < 64 && b > 0) {   // wave-parallel lookback in wave 0
        int off = 0;
        int base = b - 1;
        for (;;) {
            int idx = base - t;
            unsigned w = 0;
            if (idx >= 0) {
                do { w = atomicOr(&ps[idx], 0u); } while (!(w & (FLG_A | FLG_P)));
            }
            bool isP = (w & FLG_P) != 0;
            unsigned long long pm = __ballot(isP);
            int firstP = pm ? (__ffsll((unsigned long long)pm) - 1) : 64;
            int contrib = (idx >= 0 && t <= firstP) ? (int)(w & VAL_MASK) : 0;
#pragma unroll
            for (int sh = 32; sh > 0; sh >>= 1) contrib += __shfl_down(contrib, sh, 64);
            contrib = __shfl(contrib, 0, 64);
            off += contrib;
            if (firstP < 64 || base - 64 < 0) break;
            base -= 64;
        }
        if (t == 0) sh_off = off;
    }
    __syncthreads();
    if (i < N_NODES) nodeStart[i] = excl + sh_off;
}

// MFMA MLP: wave = 64 edges, one branch k. m staged in LDS (f16, K padded to
// 64), weights pre-packed as B-frags (6 coalesced dwordx4/lane, held in VGPRs
// -> NO scalar weight stream). Layer1: 4mt x 2nt x 2kt MFMAs; layer2:
// 4mt x 2nt. All LDS staging is wave-private -> no barriers.
// A layout: A[m=lane&15][k=quad*8+j] (m120). C/D: col=lane&15,
// row=quad*4+reg (m89, dtype-independent).
__global__ void __launch_bounds__(256) mlp_kernel(
    const int* __restrict__ perm, const int* __restrict__ ei,
    const unsigned* __restrict__ xh,
    const float* __restrict__ ea, const float* __restrict__ ew,
    const uint4* __restrict__ w1f4, const float* __restrict__ b1,
    const uint4* __restrict__ w2f4, const float* __restrict__ b2,
    const int* __restrict__ nodeStart, const int* __restrict__ slotLocal,
    const int* __restrict__ bucketFill,
    unsigned short* __restrict__ fbuf) {
    // m rows: 144B stride (64 f16 data + pad; 36e%32 -> 2-way conflict = free).
    // h rows: 80B stride (20e%32 -> 2-way). out reuses m region (m dead).
    __shared__ uint4 lds4[3584];   // 57,344 B: 4 waves x (9216 m + 5120 h)
    char* lds = (char*)lds4;

    int t = blockIdx.x * 256 + threadIdx.x;
    int u = __builtin_amdgcn_readfirstlane(t);
    int k = u >> 17;
    int fill = bucketFill[k];
    if ((u & (BCAP - 1)) >= fill) return;   // whole wave past bucket fill
    int rel = t & (BCAP - 1);
    bool valid = rel < fill;
    int e = perm[(k << 17) + min(rel, fill - 1)];  // clamp: pad slots are garbage

    int L = threadIdx.x & 63;
    int wv = threadIdx.x >> 6;
    char* mreg = lds + wv * 9216;
    char* hreg = lds + 36864 + wv * 5120;
    int quad = L >> 4, col = L & 15;

    int s = ei[e];
    int d = ei[N_EDGES + e];

    // ---- stage m (f16, zero-padded k=36..63) into LDS row L ----
    unsigned mw[18];
    const uint4* xj = ((const uint4*)xh) + 4 * (size_t)s;   // 64B bf16 row
    const uint4* xi = ((const uint4*)xh) + 4 * (size_t)d;
#pragma unroll
    for (int q = 0; q < 4; ++q) {
        uint4 a4 = xj[q], b4 = xi[q];
#pragma unroll
        for (int c = 0; c < 4; ++c) {
            unsigned ua = (&a4.x)[c], ub = (&b4.x)[c];
            float d0 = __uint_as_float(ua << 16) - __uint_as_float(ub << 16);
            float d1 = __uint_as_float(ua & 0xFFFF0000u) - __uint_as_float(ub & 0xFFFF0000u);
            mw[4 * q + c] = pk_f16pair(d0, d1);
        }
    }
    float4 eav = ((const float4*)ea)[e];
    mw[16] = pk_f16pair(eav.x, eav.y);
    mw[17] = pk_f16pair(eav.z, eav.w);
    float w = ew[e];
    int slot = valid ? (nodeStart[d] + slotLocal[e]) : 0;

    uint4* mrow = (uint4*)(mreg + L * 144);
    mrow[0] = make_uint4(mw[0], mw[1], mw[2], mw[3]);
    mrow[1] = make_uint4(mw[4], mw[5], mw[6], mw[7]);
    mrow[2] = make_uint4(mw[8], mw[9], mw[10], mw[11]);
    mrow[3] = make_uint4(mw[12], mw[13], mw[14], mw[15]);
    mrow[4] = make_uint4(mw[16], mw[17], 0u, 0u);
    mrow[5] = make_uint4(0u, 0u, 0u, 0u);
    mrow[6] = make_uint4(0u, 0u, 0u, 0u);
    mrow[7] = make_uint4(0u, 0u, 0u, 0u);

    // ---- B fragments (held in VGPRs; coalesced 16B/lane loads) ----
    half8 B1[2][2], B2[2];
#pragma unroll
    for (int kt = 0; kt < 2; ++kt)
#pragma unroll
        for (int nt = 0; nt < 2; ++nt)
            B1[kt][nt] = __builtin_bit_cast(half8, w1f4[((k * 2 + kt) * 2 + nt) * 64 + L]);
#pragma unroll
    for (int nt = 0; nt < 2; ++nt)
        B2[nt] = __builtin_bit_cast(half8, w2f4[(k * 2 + nt) * 64 + L]);
    float b1o0 = b1[k * 32 + col],      b1o1 = b1[k * 32 + 16 + col];
    float b2o0 = b2[k * 32 + col],      b2o1 = b2[k * 32 + 16 + col];

#pragma unroll
    for (int mt = 0; mt < 4; ++mt) {
        int arow = mt * 16 + col;
        half8 a0 = __builtin_bit_cast(half8, *(const uint4*)(mreg + arow * 144 + quad * 16));
        half8 a1 = __builtin_bit_cast(half8, *(const uint4*)(mreg + arow * 144 + 64 + quad * 16));
        f32x4 c0 = {b1o0, b1o0, b1o0, b1o0};
        f32x4 c1 = {b1o1, b1o1, b1o1, b1o1};
        c0 = MFMA(a0, B1[0][0], c0);
        c0 = MFMA(a1, B1[1][0], c0);
        c1 = MFMA(a0, B1[0][1], c1);
        c1 = MFMA(a1, B1[1][1], c1);
        // ReLU -> h rows (f16); row = edge, col = output channel
#pragma unroll
        for (int r = 0; r < 4; ++r) {
            int edge = mt * 16 + quad * 4 + r;
            *(unsigned short*)(hreg + edge * 80 + col * 2)        = f16bits(fmaxf(c0[r], 0.0f));
            *(unsigned short*)(hreg + edge * 80 + (16 + col) * 2) = f16bits(fmaxf(c1[r], 0.0f));
        }
        // layer 2 for this mt (h rows for mt are complete within this wave)
        half8 ah = __builtin_bit_cast(half8, *(const uint4*)(hreg + arow * 80 + quad * 16));
        f32x4 d0 = {b2o0, b2o0, b2o0, b2o0};
        f32x4 d1 = {b2o1, b2o1, b2o1, b2o1};
        d0 = MFMA(ah, B2[0], d0);
        d1 = MFMA(ah, B2[1], d1);
#pragma unroll
        for (int r = 0; r < 4; ++r) {
            int edge = mt * 16 + quad * 4 + r;
            *(unsigned short*)(mreg + edge * 144 + col * 2)        = f16bits(fmaxf(d0[r], 0.0f));
            *(unsigned short*)(mreg + edge * 144 + (16 + col) * 2) = f16bits(fmaxf(d1[r], 0.0f));
        }
    }

    // ---- read back own edge's out row, *w, pack bf16, store 64B ----
    uint4* orow = (uint4*)(mreg + L * 144);
    uint4* frow = (uint4*)(fbuf + 32 * (size_t)slot);
#pragma unroll
    for (int q = 0; q < 4; ++q) {
        uint4 v = orow[q];
        unsigned r[4];
#pragma unroll
        for (int c = 0; c < 4; ++c) {
            h2 hv = __builtin_bit_cast(h2, (&v.x)[c]);
            r[c] = pk_bf16((float)hv.x * w, (float)hv.y * w);
        }
        if (valid) frow[q] = make_uint4(r[0], r[1], r[2], r[3]);
    }
}

// 4 channels per thread: uint2 read = 4 bf16; 8 threads/node cover a 64B row.
__global__ void agg_kernel(const unsigned short* __restrict__ fbuf,
                           const int* __restrict__ nodeStart, const int* __restrict__ deg,
                           const float* __restrict__ x, const float* __restrict__ Wr,
                           const float* __restrict__ br, float* __restrict__ out) {
    int t = blockIdx.x * blockDim.x + threadIdx.x;
    if (t >= N_NODES * 8) return;
    int n = t >> 3, g8 = t & 7;          // channels 4*g8 .. 4*g8+3
    int st = nodeStart[n], dg = deg[n];
    const uint2* fb = (const uint2*)fbuf;
    float a0 = 0.0f, a1 = 0.0f, a2 = 0.0f, a3 = 0.0f;
    for (int j = 0; j < dg; ++j) {
        uint2 uu = fb[(size_t)(st + j) * 8 + g8];   // CSR-contiguous stream
        a0 += __uint_as_float(uu.x << 16);
        a1 += __uint_as_float(uu.x & 0xFFFF0000u);
        a2 += __uint_as_float(uu.y << 16);
        a3 += __uint_as_float(uu.y & 0xFFFF0000u);
    }
    float inv = 1.0f / (float)max(dg, 1);
    int o = g8 * 4;
    a0 = a0 * inv + br[o];
    a1 = a1 * inv + br[o + 1];
    a2 = a2 * inv + br[o + 2];
    a3 = a3 * inv + br[o + 3];
    const float* xr = x + 32 * (size_t)n;
#pragma unroll
    for (int c = 0; c < 32; ++c) {
        float xv = xr[c];
        a0 = fmaf(xv, Wr[c * 32 + o], a0);
        a1 = fmaf(xv, Wr[c * 32 + o + 1], a1);
        a2 = fmaf(xv, Wr[c * 32 + o + 2], a2);
        a3 = fmaf(xv, Wr[c * 32 + o + 3], a3);
    }
    float4* o4 = (float4*)(out + 32 * (size_t)n + o);
    *o4 = make_float4(a0, a1, a2, a3);
}

extern "C" void kernel_launch(void* const* d_in, const int* in_sizes, int n_in,
                              void* d_out, int out_size, void* d_ws, size_t ws_size,
                              hipStream_t stream) {
    const float* x   = (const float*)d_in[0];
    const float* pos = (const float*)d_in[1];
    const int*   ei  = (const int*)d_in[2];
    const float* ea  = (const float*)d_in[3];
    const float* ew  = (const float*)d_in[4];
    const float* W1  = (const float*)d_in[5];
    const float* b1  = (const float*)d_in[6];
    const float* W2  = (const float*)d_in[7];
    const float* b2  = (const float*)d_in[8];
    const float* Wr  = (const float*)d_in[9];
    const float* br  = (const float*)d_in[10];
    float* out = (float*)d_out;

    char* ws = (char*)d_ws;
    unsigned short* fbuf = (unsigned short*)(ws + 0);
    int* perm       = (int*)(ws + 51200000);
    int* slotLocal  = (int*)(ws + 55394304);
    int* cnt        = (int*)(ws + 58594304);
    int* bucketCur  = (int*)(ws + 58794304);
    unsigned* psLb  = (unsigned*)(ws + 58794336);
    int* nodeStart  = (int*)(ws + 58795136);
    uint4* w1f4     = (uint4*)(ws + 58995136);
    uint4* w2f4     = (uint4*)(ws + 59027904);
    unsigned* xh    = (unsigned*)(ws + 59044288);

    hipMemsetAsync(cnt, 0, 200832, stream);  // cnt + bucketCur + ps (contiguous)

    prep_kernel<<<1600, 256, 0, stream>>>(W1, W2, x, w1f4, w2f4, xh);
    pass1_kernel<<<N_EDGES / 256, 256, 0, stream>>>(ei, pos, cnt, slotLocal, bucketCur, perm);
    scan_kernel<<<SCAN_BLOCKS, 256, 0, stream>>>(cnt, psLb, nodeStart);
    mlp_kernel<<<MLP_SLOTS / 256, 256, 0, stream>>>(perm, ei, xh, ea, ew,
                                                    w1f4, b1, w2f4, b2,
                                                    nodeStart, slotLocal, bucketCur, fbuf);
    agg_kernel<<<(N_NODES * 8 + 255) / 256, 256, 0, stream>>>(fbuf, nodeStart, cnt,
                                                              x, Wr, br, out);
}

// Round 13
// 205.416 us; speedup vs baseline: 1.3727x; 1.1231x over previous
//
#include <hip/hip_runtime.h>

#define N_NODES 50000
#define N_EDGES 800000
#define K_BR    8
#define BCAP    131072           // per-bucket slot capacity (2^17); mean fill 100K
#define MLP_SLOTS (K_BR * BCAP)  // 1,048,576
#define SCAN_BLOCKS 196          // ceil(50000/256)

typedef _Float16 h2 __attribute__((ext_vector_type(2)));
typedef _Float16 half8 __attribute__((ext_vector_type(8)));
typedef float f32x4 __attribute__((ext_vector_type(4)));

#define MFMA(a, b, c) __builtin_amdgcn_mfma_f32_16x16x32_f16((a), (b), (c), 0, 0, 0)

#define VAL_MASK 0x3FFFFFFFu
#define FLG_A    0x40000000u
#define FLG_P    0x80000000u

// ---------------- workspace layout (bytes) ----------------
// fbuf      : 800,000 rows x 64 B bf16   @ 0           (51,200,000)
// payload   : MLP_SLOTS x 16 B           @ 51,200,000  (16,777,216) [fill-guarded]
// cnt(deg)  : N ints                     @ 67,977,216  (200,000)   [memset 0]
// bucketCur : 8 ints (fill counts)       @ 68,177,216  (32)        [memset 0]
// ps        : 196 uints (lookback)       @ 68,177,248  (800)       [memset 0]
// nodeStart : N ints                     @ 68,178,048  (200,000)
// w1f4      : 2048 uint4 (B-frags L1)    @ 68,378,048  (32,768)
// w2f4      : 1024 uint4 (B-frags L2)    @ 68,410,816  (16,384)
// xh        : 50,000 x 32 bf16           @ 68,427,200  (3,200,000)
// total: 71,627,200  (< proven ws floor 109,473,920)

__device__ __forceinline__ int branch_idx(float dx, float dy) {
    return (dx > 0.0f ? 1 : 0) + (dy > 0.0f ? 2 : 0) +
           ((fabsf(dx) - fabsf(dy)) > 0.0f ? 4 : 0);
}

__device__ __forceinline__ unsigned int pk_bf16(float a, float b) {
    unsigned int ua = __float_as_uint(a), ub = __float_as_uint(b);
    ua += 0x7FFFu + ((ua >> 16) & 1u);   // round-to-nearest-even
    ub += 0x7FFFu + ((ub >> 16) & 1u);
    return (ua >> 16) | (ub & 0xFFFF0000u);
}

__device__ __forceinline__ unsigned pk_f16pair(float a, float b) {
    h2 p; p.x = (_Float16)a; p.y = (_Float16)b;
    return __builtin_bit_cast(unsigned, p);
}

__device__ __forceinline__ unsigned short f16bits(float a) {
    _Float16 h = (_Float16)a;
    return __builtin_bit_cast(unsigned short, h);
}

// prep: (1) W1/W2 -> MFMA B-fragment order: B[k=quad*8+j][n=lane&15], frag
// per (kt,nt), 4 dwords (8 f16) per lane. (2) x -> bf16 mirror (3.2MB,
// L2-resident; R11 win). Layouts per m120 (A) / m89 (C/D) verified notes.
__global__ void prep_kernel(const float* __restrict__ W1, const float* __restrict__ W2,
                            const float* __restrict__ x,
                            uint4* __restrict__ w1f4, uint4* __restrict__ w2f4,
                            unsigned* __restrict__ xh) {
    int t = blockIdx.x * 256 + threadIdx.x;   // grid = 1600*256 = 409,600
    if (t < 2048) {                           // layer-1 B frags
        int L = t & 63, fl = t >> 6;
        int nt = fl & 1, kt = (fl >> 1) & 1, k = fl >> 2;
        int quad = L >> 4, col = L & 15;
        unsigned dw[4];
#pragma unroll
        for (int i = 0; i < 4; ++i) {
            float v0 = 0.0f, v1 = 0.0f;
            int k0 = kt * 32 + quad * 8 + 2 * i;
            if (k0 < 36)     v0 = W1[k * 1152 + k0 * 32 + nt * 16 + col];
            if (k0 + 1 < 36) v1 = W1[k * 1152 + (k0 + 1) * 32 + nt * 16 + col];
            dw[i] = pk_f16pair(v0, v1);
        }
        w1f4[t] = make_uint4(dw[0], dw[1], dw[2], dw[3]);
    } else if (t < 3072) {                    // layer-2 B frags
        int u2 = t - 2048;
        int L = u2 & 63, fl = u2 >> 6;
        int nt = fl & 1, k = fl >> 1;
        int quad = L >> 4, col = L & 15;
        unsigned dw[4];
#pragma unroll
        for (int i = 0; i < 4; ++i) {
            int k0 = quad * 8 + 2 * i;
            dw[i] = pk_f16pair(W2[k * 1024 + k0 * 32 + nt * 16 + col],
                               W2[k * 1024 + (k0 + 1) * 32 + nt * 16 + col]);
        }
        w2f4[u2] = make_uint4(dw[0], dw[1], dw[2], dw[3]);
    }
#pragma unroll
    for (int rep = 0; rep < 2; ++rep) {
        int j = t + rep * 409600;
        if (j < 800000) {
            float2 xv = ((const float2*)x)[j];
            xh[j] = pk_bf16(xv.x, xv.y);
        }
    }
}

// ONE pass over edges: branch histogram + bucket scatter of a packed 16B
// payload {s|d<<16, slotLocal|ew_f16<<16, ea01, ea23} + CSR rank.
// (R12 lesson: mlp is gather-latency-bound; R9 lesson: payload kills FETCH.)
// 800000 = 3125 * 256 exactly -> no bounds check.
__global__ void pass1_kernel(const int* __restrict__ ei, const float* __restrict__ pos,
                             const float* __restrict__ ea, const float* __restrict__ ew,
                             int* __restrict__ cnt, int* __restrict__ bucketCur,
                             uint4* __restrict__ payload) {
    __shared__ int h[K_BR];
    __shared__ int base[K_BR];
    int t = threadIdx.x;
    if (t < K_BR) h[t] = 0;
    __syncthreads();
    int e = blockIdx.x * 256 + t;
    int s = ei[e], d = ei[N_EDGES + e];
    float2 ps = ((const float2*)pos)[s];
    float2 pd = ((const float2*)pos)[d];
    int k = branch_idx(ps.x - pd.x, ps.y - pd.y);
    int rank = atomicAdd(&h[k], 1);
    int slotLocal = atomicAdd(&cnt[d], 1);
    float4 eav = ((const float4*)ea)[e];
    unsigned ewh = (unsigned)f16bits(ew[e]);
    __syncthreads();
    if (t < K_BR) base[t] = (h[t] > 0) ? atomicAdd(&bucketCur[t], h[t]) : 0;
    __syncthreads();
    int idx = (k << 17) + base[k] + rank;
    payload[idx] = make_uint4((unsigned)s | ((unsigned)d << 16),
                              (unsigned)slotLocal | (ewh << 16),
                              pk_f16pair(eav.x, eav.y),
                              pk_f16pair(eav.z, eav.w));
}

// single-dispatch decoupled-lookback exclusive scan (R11-proven).
__global__ void scan_kernel(const int* __restrict__ cnt, unsigned* __restrict__ ps,
                            int* __restrict__ nodeStart) {
    __shared__ int s[256];
    __shared__ int sh_off;
    int t = threadIdx.x, b = blockIdx.x;
    int i = b * 256 + t;
    int v = (i < N_NODES) ? cnt[i] : 0;
    s[t] = v;
    __syncthreads();
#pragma unroll
    for (int off = 1; off < 256; off <<= 1) {
        int tmp = (t >= off) ? s[t - off] : 0;
        __syncthreads();
        s[t] += tmp;
        __syncthreads();
    }
    int excl = s[t] - v;
    if (t == 255)
        atomicExch(&ps[b], (unsigned)s[255] | (b == 0 ? FLG_P : FLG_A));
    if (t == 0) sh_off = 0;
    if (t < 64 && b > 0) {   // wave-parallel lookback in wave 0
        int off = 0;
        int base = b - 1;
        for (;;) {
            int idx = base - t;
            unsigned w = 0;
            if (idx >= 0) {
                do { w = atomicOr(&ps[idx], 0u); } while (!(w & (FLG_A | FLG_P)));
            }
            bool isP = (w & FLG_P) != 0;
            unsigned long long pm = __ballot(isP);
            int firstP = pm ? (__ffsll((unsigned long long)pm) - 1) : 64;
            int contrib = (idx >= 0 && t <= firstP) ? (int)(w & VAL_MASK) : 0;
#pragma unroll
            for (int sh = 32; sh > 0; sh >>= 1) contrib += __shfl_down(contrib, sh, 64);
            contrib = __shfl(contrib, 0, 64);
            off += contrib;
            if (firstP < 64 || base - 64 < 0) break;
            base -= 64;
        }
        if (t == 0) sh_off = off;
    }
    __syncthreads();
    if (i < N_NODES) nodeStart[i] = excl + sh_off;
}

// MFMA MLP (R12-verified layouts), now: single coalesced 16B payload read per
// edge (no ei/ea/ew/slotLocal gathers), per-mt h buffer + 128-thread blocks
// -> LDS 20,992B/block -> 7 blocks/CU = 14 waves (was 2 blocks / 19%).
__global__ void __launch_bounds__(128) mlp_kernel(
    const uint4* __restrict__ payload,
    const unsigned* __restrict__ xh,
    const uint4* __restrict__ w1f4, const float* __restrict__ b1,
    const uint4* __restrict__ w2f4, const float* __restrict__ b2,
    const int* __restrict__ nodeStart,
    const int* __restrict__ bucketFill,
    unsigned short* __restrict__ fbuf) {
    // per wave: m = 64 rows x 144B (9216) + h = 16 rows x 80B (1280) = 10,496B
    __shared__ uint4 lds4[1312];   // 20,992 B for 2 waves
    char* lds = (char*)lds4;

    int t = blockIdx.x * 128 + threadIdx.x;
    int u = __builtin_amdgcn_readfirstlane(t);
    int k = u >> 17;
    int fill = bucketFill[k];
    if ((u & (BCAP - 1)) >= fill) return;   // whole wave past bucket fill
    int rel = t & (BCAP - 1);
    bool valid = rel < fill;
    int idx = (k << 17) + min(rel, fill - 1);  // clamp: pad slots are garbage

    int L = threadIdx.x & 63;
    int wv = threadIdx.x >> 6;
    char* mreg = lds + wv * 10496;
    char* hreg = mreg + 9216;
    int quad = L >> 4, col = L & 15;

    uint4 pl = payload[idx];
    int s = (int)(pl.x & 0xFFFFu);
    int d = (int)(pl.x >> 16);
    float w = (float)__builtin_bit_cast(_Float16, (unsigned short)(pl.y >> 16));
    int slot = valid ? (nodeStart[d] + (int)(pl.y & 0xFFFFu)) : 0;

    // ---- stage m (f16, zero-padded k=36..63) into LDS row L ----
    unsigned mw[16];
    const uint4* xj = ((const uint4*)xh) + 4 * (size_t)s;   // 64B bf16 row
    const uint4* xi = ((const uint4*)xh) + 4 * (size_t)d;
#pragma unroll
    for (int q = 0; q < 4; ++q) {
        uint4 a4 = xj[q], b4 = xi[q];
#pragma unroll
        for (int c = 0; c < 4; ++c) {
            unsigned ua = (&a4.x)[c], ub = (&b4.x)[c];
            float d0 = __uint_as_float(ua << 16) - __uint_as_float(ub << 16);
            float d1 = __uint_as_float(ua & 0xFFFF0000u) - __uint_as_float(ub & 0xFFFF0000u);
            mw[4 * q + c] = pk_f16pair(d0, d1);
        }
    }

    uint4* mrow = (uint4*)(mreg + L * 144);
    mrow[0] = make_uint4(mw[0], mw[1], mw[2], mw[3]);
    mrow[1] = make_uint4(mw[4], mw[5], mw[6], mw[7]);
    mrow[2] = make_uint4(mw[8], mw[9], mw[10], mw[11]);
    mrow[3] = make_uint4(mw[12], mw[13], mw[14], mw[15]);
    mrow[4] = make_uint4(pl.z, pl.w, 0u, 0u);
    mrow[5] = make_uint4(0u, 0u, 0u, 0u);
    mrow[6] = make_uint4(0u, 0u, 0u, 0u);
    mrow[7] = make_uint4(0u, 0u, 0u, 0u);

    // ---- B fragments (held in VGPRs; coalesced 16B/lane loads) ----
    half8 B1[2][2], B2[2];
#pragma unroll
    for (int kt = 0; kt < 2; ++kt)
#pragma unroll
        for (int nt = 0; nt < 2; ++nt)
            B1[kt][nt] = __builtin_bit_cast(half8, w1f4[((k * 2 + kt) * 2 + nt) * 64 + L]);
#pragma unroll
    for (int nt = 0; nt < 2; ++nt)
        B2[nt] = __builtin_bit_cast(half8, w2f4[(k * 2 + nt) * 64 + L]);
    float b1o0 = b1[k * 32 + col],      b1o1 = b1[k * 32 + 16 + col];
    float b2o0 = b2[k * 32 + col],      b2o1 = b2[k * 32 + 16 + col];

#pragma unroll
    for (int mt = 0; mt < 4; ++mt) {
        int arow = mt * 16 + col;
        half8 a0 = __builtin_bit_cast(half8, *(const uint4*)(mreg + arow * 144 + quad * 16));
        half8 a1 = __builtin_bit_cast(half8, *(const uint4*)(mreg + arow * 144 + 64 + quad * 16));
        f32x4 c0 = {b1o0, b1o0, b1o0, b1o0};
        f32x4 c1 = {b1o1, b1o1, b1o1, b1o1};
        c0 = MFMA(a0, B1[0][0], c0);
        c0 = MFMA(a1, B1[1][0], c0);
        c1 = MFMA(a0, B1[0][1], c1);
        c1 = MFMA(a1, B1[1][1], c1);
        // ReLU -> per-mt h buffer (16 edges x 32 ch, f16); wave-synchronous
#pragma unroll
        for (int r = 0; r < 4; ++r) {
            int er = quad * 4 + r;
            *(unsigned short*)(hreg + er * 80 + col * 2)        = f16bits(fmaxf(c0[r], 0.0f));
            *(unsigned short*)(hreg + er * 80 + (16 + col) * 2) = f16bits(fmaxf(c1[r], 0.0f));
        }
        // layer 2 for this mt
        half8 ah = __builtin_bit_cast(half8, *(const uint4*)(hreg + col * 80 + quad * 16));
        f32x4 d0 = {b2o0, b2o0, b2o0, b2o0};
        f32x4 d1 = {b2o1, b2o1, b2o1, b2o1};
        d0 = MFMA(ah, B2[0], d0);
        d1 = MFMA(ah, B2[1], d1);
#pragma unroll
        for (int r = 0; r < 4; ++r) {
            int edge = mt * 16 + quad * 4 + r;
            *(unsigned short*)(mreg + edge * 144 + col * 2)        = f16bits(fmaxf(d0[r], 0.0f));
            *(unsigned short*)(mreg + edge * 144 + (16 + col) * 2) = f16bits(fmaxf(d1[r], 0.0f));
        }
    }

    // ---- read back own edge's out row, *w, pack bf16, store 64B ----
    uint4* orow = (uint4*)(mreg + L * 144);
    uint4* frow = (uint4*)(fbuf + 32 * (size_t)slot);
#pragma unroll
    for (int q = 0; q < 4; ++q) {
        uint4 v = orow[q];
        unsigned r[4];
#pragma unroll
        for (int c = 0; c < 4; ++c) {
            h2 hv = __builtin_bit_cast(h2, (&v.x)[c]);
            r[c] = pk_bf16((float)hv.x * w, (float)hv.y * w);
        }
        if (valid) frow[q] = make_uint4(r[0], r[1], r[2], r[3]);
    }
}

// 4 channels per thread: uint2 read = 4 bf16; 8 threads/node cover a 64B row.
__global__ void agg_kernel(const unsigned short* __restrict__ fbuf,
                           const int* __restrict__ nodeStart, const int* __restrict__ deg,
                           const float* __restrict__ x, const float* __restrict__ Wr,
                           const float* __restrict__ br, float* __restrict__ out) {
    int t = blockIdx.x * blockDim.x + threadIdx.x;
    if (t >= N_NODES * 8) return;
    int n = t >> 3, g8 = t & 7;          // channels 4*g8 .. 4*g8+3
    int st = nodeStart[n], dg = deg[n];
    const uint2* fb = (const uint2*)fbuf;
    float a0 = 0.0f, a1 = 0.0f, a2 = 0.0f, a3 = 0.0f;
    for (int j = 0; j < dg; ++j) {
        uint2 uu = fb[(size_t)(st + j) * 8 + g8];   // CSR-contiguous stream
        a0 += __uint_as_float(uu.x << 16);
        a1 += __uint_as_float(uu.x & 0xFFFF0000u);
        a2 += __uint_as_float(uu.y << 16);
        a3 += __uint_as_float(uu.y & 0xFFFF0000u);
    }
    float inv = 1.0f / (float)max(dg, 1);
    int o = g8 * 4;
    a0 = a0 * inv + br[o];
    a1 = a1 * inv + br[o + 1];
    a2 = a2 * inv + br[o + 2];
    a3 = a3 * inv + br[o + 3];
    const float* xr = x + 32 * (size_t)n;
#pragma unroll
    for (int c = 0; c < 32; ++c) {
        float xv = xr[c];
        a0 = fmaf(xv, Wr[c * 32 + o], a0);
        a1 = fmaf(xv, Wr[c * 32 + o + 1], a1);
        a2 = fmaf(xv, Wr[c * 32 + o + 2], a2);
        a3 = fmaf(xv, Wr[c * 32 + o + 3], a3);
    }
    float4* o4 = (float4*)(out + 32 * (size_t)n + o);
    *o4 = make_float4(a0, a1, a2, a3);
}

extern "C" void kernel_launch(void* const* d_in, const int* in_sizes, int n_in,
                              void* d_out, int out_size, void* d_ws, size_t ws_size,
                              hipStream_t stream) {
    const float* x   = (const float*)d_in[0];
    const float* pos = (const float*)d_in[1];
    const int*   ei  = (const int*)d_in[2];
    const float* ea  = (const float*)d_in[3];
    const float* ew  = (const float*)d_in[4];
    const float* W1  = (const float*)d_in[5];
    const float* b1  = (const float*)d_in[6];
    const float* W2  = (const float*)d_in[7];
    const float* b2  = (const float*)d_in[8];
    const float* Wr  = (const float*)d_in[9];
    const float* br  = (const float*)d_in[10];
    float* out = (float*)d_out;

    char* ws = (char*)d_ws;
    unsigned short* fbuf = (unsigned short*)(ws + 0);
    uint4* payload  = (uint4*)(ws + 51200000);
    int* cnt        = (int*)(ws + 67977216);
    int* bucketCur  = (int*)(ws + 68177216);
    unsigned* psLb  = (unsigned*)(ws + 68177248);
    int* nodeStart  = (int*)(ws + 68178048);
    uint4* w1f4     = (uint4*)(ws + 68378048);
    uint4* w2f4     = (uint4*)(ws + 68410816);
    unsigned* xh    = (unsigned*)(ws + 68427200);

    hipMemsetAsync(cnt, 0, 200832, stream);  // cnt + bucketCur + ps (contiguous)

    prep_kernel<<<1600, 256, 0, stream>>>(W1, W2, x, w1f4, w2f4, xh);
    pass1_kernel<<<N_EDGES / 256, 256, 0, stream>>>(ei, pos, ea, ew, cnt, bucketCur, payload);
    scan_kernel<<<SCAN_BLOCKS, 256, 0, stream>>>(cnt, psLb, nodeStart);
    mlp_kernel<<<MLP_SLOTS / 128, 128, 0, stream>>>(payload, xh, w1f4, b1, w2f4, b2,
                                                    nodeStart, bucketCur, fbuf);
    agg_kernel<<<(N_NODES * 8 + 255) / 256, 256, 0, stream>>>(fbuf, nodeStart, cnt,
                                                              x, Wr, br, out);
}

// Round 14
// 199.853 us; speedup vs baseline: 1.4109x; 1.0278x over previous
//
#include <hip/hip_runtime.h>

#define N_NODES 50000
#define N_EDGES 800000
#define K_BR    8
#define BCAP    131072           // per-bucket slot capacity (2^17); mean fill 100K
#define MLP_SLOTS (K_BR * BCAP)  // 1,048,576
#define SCAN_BLOCKS 196          // ceil(50000/256)

typedef _Float16 h2 __attribute__((ext_vector_type(2)));
typedef _Float16 half8 __attribute__((ext_vector_type(8)));
typedef float f32x4 __attribute__((ext_vector_type(4)));

#define MFMA(a, b, c) __builtin_amdgcn_mfma_f32_16x16x32_f16((a), (b), (c), 0, 0, 0)

#define VAL_MASK 0x3FFFFFFFu
#define FLG_A    0x40000000u
#define FLG_P    0x80000000u

// ---------------- workspace layout (bytes) ----------------
// fbuf      : 800,000 rows x 64 B f16    @ 0           (51,200,000)
// payload   : MLP_SLOTS x 16 B           @ 51,200,000  (16,777,216) [fill-guarded]
// cnt(deg)  : N ints                     @ 67,977,216  (200,000)   [memset 0]
// bucketCur : 8 ints (fill counts)       @ 68,177,216  (32)        [memset 0]
// ps        : 196 uints (lookback)       @ 68,177,248  (800)       [memset 0]
// nodeStart : N ints                     @ 68,178,048  (200,000)
// w1f4      : 2048 uint4 (B-frags L1)    @ 68,378,048  (32,768)
// w2f4      : 1024 uint4 (B-frags L2)    @ 68,410,816  (16,384)
// xh        : 50,000 x 32 f16            @ 68,427,200  (3,200,000)
// total: 71,627,200  (< proven ws floor 109,473,920)

__device__ __forceinline__ int branch_idx(float dx, float dy) {
    return (dx > 0.0f ? 1 : 0) + (dy > 0.0f ? 2 : 0) +
           ((fabsf(dx) - fabsf(dy)) > 0.0f ? 4 : 0);
}

__device__ __forceinline__ unsigned pk_f16pair(float a, float b) {
    h2 p; p.x = (_Float16)a; p.y = (_Float16)b;
    return __builtin_bit_cast(unsigned, p);
}

__device__ __forceinline__ unsigned short f16bits(float a) {
    _Float16 h = (_Float16)a;
    return __builtin_bit_cast(unsigned short, h);
}

// ONE pass over edges, now also absorbing prep (R13: fold dispatches):
//  - branch histogram + bucket scatter of packed 16B payload + CSR rank
//  - x -> f16 mirror (1 float2/thread, exact cover: 3125*256 = 800000)
//  - threads t<3072 pack W1/W2 MFMA B-frags (B[k=quad*8+j][n=lane&15], m120)
__global__ void pass1_kernel(const int* __restrict__ ei, const float* __restrict__ pos,
                             const float* __restrict__ ea, const float* __restrict__ ew,
                             const float* __restrict__ x,
                             const float* __restrict__ W1, const float* __restrict__ W2,
                             int* __restrict__ cnt, int* __restrict__ bucketCur,
                             uint4* __restrict__ payload, unsigned* __restrict__ xh,
                             uint4* __restrict__ w1f4, uint4* __restrict__ w2f4) {
    __shared__ int h[K_BR];
    __shared__ int base[K_BR];
    int t = threadIdx.x;
    int e = blockIdx.x * 256 + t;
    if (t < K_BR) h[t] = 0;

    // x mirror: one float2 per thread (f16 pair — more precise than bf16)
    float2 xv = ((const float2*)x)[e];
    xh[e] = pk_f16pair(xv.x, xv.y);

    // W fragments (first 12 blocks only)
    if (e < 2048) {                           // layer-1 B frags
        int L = e & 63, fl = e >> 6;
        int nt = fl & 1, kt = (fl >> 1) & 1, k = fl >> 2;
        int quad = L >> 4, col = L & 15;
        unsigned dw[4];
#pragma unroll
        for (int i = 0; i < 4; ++i) {
            float v0 = 0.0f, v1 = 0.0f;
            int k0 = kt * 32 + quad * 8 + 2 * i;
            if (k0 < 36)     v0 = W1[k * 1152 + k0 * 32 + nt * 16 + col];
            if (k0 + 1 < 36) v1 = W1[k * 1152 + (k0 + 1) * 32 + nt * 16 + col];
            dw[i] = pk_f16pair(v0, v1);
        }
        w1f4[e] = make_uint4(dw[0], dw[1], dw[2], dw[3]);
    } else if (e < 3072) {                    // layer-2 B frags
        int u2 = e - 2048;
        int L = u2 & 63, fl = u2 >> 6;
        int nt = fl & 1, k = fl >> 1;
        int quad = L >> 4, col = L & 15;
        unsigned dw[4];
#pragma unroll
        for (int i = 0; i < 4; ++i) {
            int k0 = quad * 8 + 2 * i;
            dw[i] = pk_f16pair(W2[k * 1024 + k0 * 32 + nt * 16 + col],
                               W2[k * 1024 + (k0 + 1) * 32 + nt * 16 + col]);
        }
        w2f4[u2] = make_uint4(dw[0], dw[1], dw[2], dw[3]);
    }

    __syncthreads();
    int s = ei[e], d = ei[N_EDGES + e];
    float2 ps = ((const float2*)pos)[s];
    float2 pd = ((const float2*)pos)[d];
    int k = branch_idx(ps.x - pd.x, ps.y - pd.y);
    int rank = atomicAdd(&h[k], 1);
    int slotLocal = atomicAdd(&cnt[d], 1);
    float4 eav = ((const float4*)ea)[e];
    unsigned ewh = (unsigned)f16bits(ew[e]);
    __syncthreads();
    if (t < K_BR) base[t] = (h[t] > 0) ? atomicAdd(&bucketCur[t], h[t]) : 0;
    __syncthreads();
    int idx = (k << 17) + base[k] + rank;
    payload[idx] = make_uint4((unsigned)s | ((unsigned)d << 16),
                              (unsigned)slotLocal | (ewh << 16),
                              pk_f16pair(eav.x, eav.y),
                              pk_f16pair(eav.z, eav.w));
}

// single-dispatch decoupled-lookback exclusive scan (R11-proven).
__global__ void scan_kernel(const int* __restrict__ cnt, unsigned* __restrict__ ps,
                            int* __restrict__ nodeStart) {
    __shared__ int s[256];
    __shared__ int sh_off;
    int t = threadIdx.x, b = blockIdx.x;
    int i = b * 256 + t;
    int v = (i < N_NODES) ? cnt[i] : 0;
    s[t] = v;
    __syncthreads();
#pragma unroll
    for (int off = 1; off < 256; off <<= 1) {
        int tmp = (t >= off) ? s[t - off] : 0;
        __syncthreads();
        s[t] += tmp;
        __syncthreads();
    }
    int excl = s[t] - v;
    if (t == 255)
        atomicExch(&ps[b], (unsigned)s[255] | (b == 0 ? FLG_P : FLG_A));
    if (t == 0) sh_off = 0;
    if (t < 64 && b > 0) {   // wave-parallel lookback in wave 0
        int off = 0;
        int base = b - 1;
        for (;;) {
            int idx = base - t;
            unsigned w = 0;
            if (idx >= 0) {
                do { w = atomicOr(&ps[idx], 0u); } while (!(w & (FLG_A | FLG_P)));
            }
            bool isP = (w & FLG_P) != 0;
            unsigned long long pm = __ballot(isP);
            int firstP = pm ? (__ffsll((unsigned long long)pm) - 1) : 64;
            int contrib = (idx >= 0 && t <= firstP) ? (int)(w & VAL_MASK) : 0;
#pragma unroll
            for (int sh = 32; sh > 0; sh >>= 1) contrib += __shfl_down(contrib, sh, 64);
            contrib = __shfl(contrib, 0, 64);
            off += contrib;
            if (firstP < 64 || base - 64 < 0) break;
            base -= 64;
        }
        if (t == 0) sh_off = off;
    }
    __syncthreads();
    if (i < N_NODES) nodeStart[i] = excl + sh_off;
}

// MFMA MLP (R12-verified layouts). R14: 64-thread single-wave blocks ->
// LDS 10,496 B/block -> 15 blocks = 15 waves/CU (was 7x2=14 at 21KB);
// f16 xh -> m staging is 4 packed half8 subs; f16 fbuf -> store is pk_mul.
__global__ void __launch_bounds__(64) mlp_kernel(
    const uint4* __restrict__ payload,
    const unsigned* __restrict__ xh,
    const uint4* __restrict__ w1f4, const float* __restrict__ b1,
    const uint4* __restrict__ w2f4, const float* __restrict__ b2,
    const int* __restrict__ nodeStart,
    const int* __restrict__ bucketFill,
    unsigned short* __restrict__ fbuf) {
    // m = 64 rows x 144B (9216) + h = 16 rows x 80B (1280) = 10,496 B
    __shared__ uint4 lds4[656];
    char* mreg = (char*)lds4;
    char* hreg = mreg + 9216;

    int t = blockIdx.x * 64 + threadIdx.x;
    int u = __builtin_amdgcn_readfirstlane(t);
    int k = u >> 17;
    int fill = bucketFill[k];
    if ((u & (BCAP - 1)) >= fill) return;   // whole wave past bucket fill
    int rel = t & (BCAP - 1);
    bool valid = rel < fill;
    int idx = (k << 17) + min(rel, fill - 1);  // clamp: pad slots are garbage

    int L = threadIdx.x;
    int quad = L >> 4, col = L & 15;

    uint4 pl = payload[idx];
    int s = (int)(pl.x & 0xFFFFu);
    int d = (int)(pl.x >> 16);
    _Float16 wh = __builtin_bit_cast(_Float16, (unsigned short)(pl.y >> 16));
    int slot = valid ? (nodeStart[d] + (int)(pl.y & 0xFFFFu)) : 0;

    // ---- stage m (f16, zero-padded k=36..63): packed half8 subtract ----
    const uint4* xj = ((const uint4*)xh) + 4 * (size_t)s;   // 64B f16 row
    const uint4* xi = ((const uint4*)xh) + 4 * (size_t)d;
    uint4* mrow = (uint4*)(mreg + L * 144);
#pragma unroll
    for (int q = 0; q < 4; ++q) {
        half8 a8 = __builtin_bit_cast(half8, xj[q]);
        half8 b8 = __builtin_bit_cast(half8, xi[q]);
        half8 d8 = a8 - b8;
        mrow[q] = __builtin_bit_cast(uint4, d8);
    }
    mrow[4] = make_uint4(pl.z, pl.w, 0u, 0u);
    mrow[5] = make_uint4(0u, 0u, 0u, 0u);
    mrow[6] = make_uint4(0u, 0u, 0u, 0u);
    mrow[7] = make_uint4(0u, 0u, 0u, 0u);

    // ---- B fragments (held in VGPRs; coalesced 16B/lane loads) ----
    half8 B1[2][2], B2[2];
#pragma unroll
    for (int kt = 0; kt < 2; ++kt)
#pragma unroll
        for (int nt = 0; nt < 2; ++nt)
            B1[kt][nt] = __builtin_bit_cast(half8, w1f4[((k * 2 + kt) * 2 + nt) * 64 + L]);
#pragma unroll
    for (int nt = 0; nt < 2; ++nt)
        B2[nt] = __builtin_bit_cast(half8, w2f4[(k * 2 + nt) * 64 + L]);
    float b1o0 = b1[k * 32 + col],      b1o1 = b1[k * 32 + 16 + col];
    float b2o0 = b2[k * 32 + col],      b2o1 = b2[k * 32 + 16 + col];

#pragma unroll
    for (int mt = 0; mt < 4; ++mt) {
        int arow = mt * 16 + col;
        half8 a0 = __builtin_bit_cast(half8, *(const uint4*)(mreg + arow * 144 + quad * 16));
        half8 a1 = __builtin_bit_cast(half8, *(const uint4*)(mreg + arow * 144 + 64 + quad * 16));
        f32x4 c0 = {b1o0, b1o0, b1o0, b1o0};
        f32x4 c1 = {b1o1, b1o1, b1o1, b1o1};
        c0 = MFMA(a0, B1[0][0], c0);
        c0 = MFMA(a1, B1[1][0], c0);
        c1 = MFMA(a0, B1[0][1], c1);
        c1 = MFMA(a1, B1[1][1], c1);
        // ReLU -> per-mt h buffer (16 edges x 32 ch, f16); wave-synchronous
#pragma unroll
        for (int r = 0; r < 4; ++r) {
            int er = quad * 4 + r;
            *(unsigned short*)(hreg + er * 80 + col * 2)        = f16bits(fmaxf(c0[r], 0.0f));
            *(unsigned short*)(hreg + er * 80 + (16 + col) * 2) = f16bits(fmaxf(c1[r], 0.0f));
        }
        // layer 2 for this mt
        half8 ah = __builtin_bit_cast(half8, *(const uint4*)(hreg + col * 80 + quad * 16));
        f32x4 d0 = {b2o0, b2o0, b2o0, b2o0};
        f32x4 d1 = {b2o1, b2o1, b2o1, b2o1};
        d0 = MFMA(ah, B2[0], d0);
        d1 = MFMA(ah, B2[1], d1);
#pragma unroll
        for (int r = 0; r < 4; ++r) {
            int edge = mt * 16 + quad * 4 + r;
            *(unsigned short*)(mreg + edge * 144 + col * 2)        = f16bits(fmaxf(d0[r], 0.0f));
            *(unsigned short*)(mreg + edge * 144 + (16 + col) * 2) = f16bits(fmaxf(d1[r], 0.0f));
        }
    }

    // ---- read back own edge's out row, *w (packed f16), store 64B ----
    half8 w8 = {wh, wh, wh, wh, wh, wh, wh, wh};
    uint4* orow = (uint4*)(mreg + L * 144);
    uint4* frow = (uint4*)(fbuf + 32 * (size_t)slot);
#pragma unroll
    for (int q = 0; q < 4; ++q) {
        half8 v8 = __builtin_bit_cast(half8, orow[q]);
        v8 = v8 * w8;
        if (valid) frow[q] = __builtin_bit_cast(uint4, v8);
    }
}

// 4 channels per thread: uint2 read = 4 f16; 8 threads/node cover a 64B row.
__global__ void agg_kernel(const unsigned short* __restrict__ fbuf,
                           const int* __restrict__ nodeStart, const int* __restrict__ deg,
                           const float* __restrict__ x, const float* __restrict__ Wr,
                           const float* __restrict__ br, float* __restrict__ out) {
    int t = blockIdx.x * blockDim.x + threadIdx.x;
    if (t >= N_NODES * 8) return;
    int n = t >> 3, g8 = t & 7;          // channels 4*g8 .. 4*g8+3
    int st = nodeStart[n], dg = deg[n];
    const uint2* fb = (const uint2*)fbuf;
    float a0 = 0.0f, a1 = 0.0f, a2 = 0.0f, a3 = 0.0f;
    for (int j = 0; j < dg; ++j) {
        uint2 uu = fb[(size_t)(st + j) * 8 + g8];   // CSR-contiguous stream
        h2 p01 = __builtin_bit_cast(h2, uu.x);
        h2 p23 = __builtin_bit_cast(h2, uu.y);
        a0 += (float)p01.x;
        a1 += (float)p01.y;
        a2 += (float)p23.x;
        a3 += (float)p23.y;
    }
    float inv = 1.0f / (float)max(dg, 1);
    int o = g8 * 4;
    a0 = a0 * inv + br[o];
    a1 = a1 * inv + br[o + 1];
    a2 = a2 * inv + br[o + 2];
    a3 = a3 * inv + br[o + 3];
    const float* xr = x + 32 * (size_t)n;
#pragma unroll
    for (int c = 0; c < 32; ++c) {
        float xv = xr[c];
        a0 = fmaf(xv, Wr[c * 32 + o], a0);
        a1 = fmaf(xv, Wr[c * 32 + o + 1], a1);
        a2 = fmaf(xv, Wr[c * 32 + o + 2], a2);
        a3 = fmaf(xv, Wr[c * 32 + o + 3], a3);
    }
    float4* o4 = (float4*)(out + 32 * (size_t)n + o);
    *o4 = make_float4(a0, a1, a2, a3);
}

extern "C" void kernel_launch(void* const* d_in, const int* in_sizes, int n_in,
                              void* d_out, int out_size, void* d_ws, size_t ws_size,
                              hipStream_t stream) {
    const float* x   = (const float*)d_in[0];
    const float* pos = (const float*)d_in[1];
    const int*   ei  = (const int*)d_in[2];
    const float* ea  = (const float*)d_in[3];
    const float* ew  = (const float*)d_in[4];
    const float* W1  = (const float*)d_in[5];
    const float* b1  = (const float*)d_in[6];
    const float* W2  = (const float*)d_in[7];
    const float* b2  = (const float*)d_in[8];
    const float* Wr  = (const float*)d_in[9];
    const float* br  = (const float*)d_in[10];
    float* out = (float*)d_out;

    char* ws = (char*)d_ws;
    unsigned short* fbuf = (unsigned short*)(ws + 0);
    uint4* payload  = (uint4*)(ws + 51200000);
    int* cnt        = (int*)(ws + 67977216);
    int* bucketCur  = (int*)(ws + 68177216);
    unsigned* psLb  = (unsigned*)(ws + 68177248);
    int* nodeStart  = (int*)(ws + 68178048);
    uint4* w1f4     = (uint4*)(ws + 68378048);
    uint4* w2f4     = (uint4*)(ws + 68410816);
    unsigned* xh    = (unsigned*)(ws + 68427200);

    hipMemsetAsync(cnt, 0, 200832, stream);  // cnt + bucketCur + ps (contiguous)

    pass1_kernel<<<N_EDGES / 256, 256, 0, stream>>>(ei, pos, ea, ew, x, W1, W2,
                                                    cnt, bucketCur, payload, xh,
                                                    w1f4, w2f4);
    scan_kernel<<<SCAN_BLOCKS, 256, 0, stream>>>(cnt, psLb, nodeStart);
    mlp_kernel<<<MLP_SLOTS / 64, 64, 0, stream>>>(payload, xh, w1f4, b1, w2f4, b2,
                                                  nodeStart, bucketCur, fbuf);
    agg_kernel<<<(N_NODES * 8 + 255) / 256, 256, 0, stream>>>(fbuf, nodeStart, cnt,
                                                              x, Wr, br, out);
}